// Round 16
// baseline (135.001 us; speedup 1.0000x reference)
//
#include <hip/hip_runtime.h>
#include <math.h>

#define VOCAB 20000
#define E     300
#define EP    320          // padded K for proj GEMM (10 k-steps of 32)
#define H     1024
#define G     8
#define NOUT  300
#define NP    320          // padded N for outproj
#define KOUT  8192         // G*H
#define NANS  4000
#define B     64
#define NQ    32
#define NK    256

typedef __attribute__((ext_vector_type(8))) short bf16x8;
typedef __attribute__((ext_vector_type(4))) float f32x4;

__device__ inline ushort f2bf(float x) {
    union { float f; unsigned u; } c; c.f = x;
    unsigned r = c.u + 0x7FFF + ((c.u >> 16) & 1);   // RNE
    return (ushort)(r >> 16);
}
__device__ inline float bf2f(ushort x) {
    union { unsigned u; float f; } c; c.u = ((unsigned)x) << 16;
    return c.f;
}
#define MFMA(a, b, c) __builtin_amdgcn_mfma_f32_16x16x32_bf16((a), (b), (c), 0, 0, 0)

// ---------------------------------------------------------------------------
// P0: merged weight prep. 800 blocks:
//   id <  160: WT[h][e] tiles from Wq/Wk (64h x 64e, f32 LDS bounce)
//   id >= 160: woutT[n][k] tiles from Wout (64k x 64n)
// ---------------------------------------------------------------------------
__global__ __launch_bounds__(256) void prep_weights(
    const float* __restrict__ Wq, const float* __restrict__ Wk,
    const float* __restrict__ Wout,
    ushort* __restrict__ WTq, ushort* __restrict__ WTk,
    ushort* __restrict__ woutT)
{
    __shared__ __align__(16) float lf[64 * 65];      // 16,640 B (aliased)
    const int id = blockIdx.x;
    const int t = threadIdx.x;

    if (id < 160) {
        const int hT = id % 16, eT = (id / 16) % 5, z = id / 80;
        const float* W = z ? Wk : Wq;
        ushort* WT = z ? WTk : WTq;
        const int h0 = hT * 64, e0 = eT * 64;

        for (int i = t; i < 64 * 64; i += 256) {     // coalesced along h
            int ec = i >> 6, hh = i & 63;
            int e = e0 + ec;
            lf[hh * 65 + ec] = (e < E) ? W[(long)e * H + h0 + hh] : 0.f;
        }
        __syncthreads();
        for (int i = t; i < 64 * 16; i += 256) {     // contiguous along e
            int hh = i >> 4, c = i & 15;
            ushort4 o;
            o.x = f2bf(lf[hh * 65 + c * 4 + 0]);
            o.y = f2bf(lf[hh * 65 + c * 4 + 1]);
            o.z = f2bf(lf[hh * 65 + c * 4 + 2]);
            o.w = f2bf(lf[hh * 65 + c * 4 + 3]);
            *(ushort4*)(WT + (long)(h0 + hh) * EP + e0 + c * 4) = o;
        }
    } else {
        ushort* td = (ushort*)lf;                    // [64][72]
        const int wid = id - 160;
        const int k0 = (wid & 127) * 64, n0 = (wid >> 7) * 64;
        for (int i = t; i < 64 * 64; i += 256) {
            int kk = i >> 6, nn = i & 63;
            int n = n0 + nn;
            float v = (n < NOUT) ? Wout[(long)(k0 + kk) * NOUT + n] : 0.f;
            td[nn * 72 + kk] = f2bf(v);
        }
        __syncthreads();
        for (int i = t; i < 64 * 8; i += 256) {
            int nn = i >> 3, c = i & 7;
            *(bf16x8*)(woutT + (long)(n0 + nn) * KOUT + k0 + c * 8) =
                *(const bf16x8*)(&td[nn * 72 + c * 8]);
        }
    }
}

// ---------------------------------------------------------------------------
// P1: merged gather-GEMM for hq and hk. grid (144, 8) x 256:
//   x < 16 : q-tiles  (rows of he_q; out hq_bf)
//   x >= 16: k-tiles  (rows of he_kg; out hk_bf + hkT)
// 128x128 tile, 4 waves, BK=32 x 10; A gathered DIRECTLY from f32 emb.
// T14 async-stage: step kk+1's gather issued into regs before COMPUTE(kk),
// so HBM gather latency hides under MFMA + barriers instead of the stage phase.
// ---------------------------------------------------------------------------
__global__ __launch_bounds__(256, 4) void proj_all(
    const int* __restrict__ he_q, const int* __restrict__ he_k,
    const float* __restrict__ emb,
    const ushort* __restrict__ WTq, const ushort* __restrict__ WTk,
    const float* __restrict__ bq, const float* __restrict__ bk,
    ushort* __restrict__ hq_bf, ushort* __restrict__ hk_bf,
    ushort* __restrict__ hkT)
{
    __shared__ ushort lds[10240];                    // 20,480 B (aliased)
    __shared__ int sidx[128];
    const bool isq = blockIdx.x < 16;
    const int xt = isq ? blockIdx.x : blockIdx.x - 16;
    const int* __restrict__ idx = isq ? he_q : he_k;
    const ushort* __restrict__ WT = isq ? WTq : WTk;
    const float* __restrict__ bias = isq ? bq : bk;
    ushort* __restrict__ outr = isq ? hq_bf : hk_bf;
    const int r0 = xt * 128;
    const int n0 = blockIdx.y * 128;
    const int t = threadIdx.x;

    if (t < 128) sidx[t] = idx[r0 + t];

    const int w = t >> 6, l = t & 63, lr = l & 15, lc = l >> 4;
    const int wm = (w >> 1) * 64, wn = (w & 1) * 64;
    const int srow = t >> 2;                         // staging row (64/pass)
    const int scol = (t & 3) * 8;                    // staging elem offset
    ushort* As = lds;                                // [128][40]
    ushort* Bs = lds + 5120;                         // [128][40]
    f32x4 acc[4][4] = {};

    __syncthreads();                                 // sidx ready

    const float* src0 = emb + (long)sidx[srow] * E;
    const float* src1 = emb + (long)sidx[64 + srow] * E;

#define GATHER(kk, A0, A1, A2, A3)                                            \
    {                                                                         \
        const int e0 = (kk) * 32 + scol;                                      \
        if (e0 + 8 <= E) {                                                    \
            A0 = *(const float4*)(src0 + e0);                                 \
            A1 = *(const float4*)(src0 + e0 + 4);                             \
            A2 = *(const float4*)(src1 + e0);                                 \
            A3 = *(const float4*)(src1 + e0 + 4);                             \
        } else {                                                              \
            float tt[16];                                                     \
            _Pragma("unroll")                                                 \
            for (int j = 0; j < 8; ++j) {                                     \
                tt[j]     = (e0 + j < E) ? src0[e0 + j] : 0.f;                \
                tt[8 + j] = (e0 + j < E) ? src1[e0 + j] : 0.f;                \
            }                                                                 \
            A0 = *(float4*)(tt);     A1 = *(float4*)(tt + 4);                 \
            A2 = *(float4*)(tt + 8); A3 = *(float4*)(tt + 12);                \
        }                                                                     \
    }

#define STOREA(A0, A1, A2, A3)                                                \
    {                                                                         \
        bf16x8 o;                                                             \
        o[0] = (short)f2bf(A0.x); o[1] = (short)f2bf(A0.y);                   \
        o[2] = (short)f2bf(A0.z); o[3] = (short)f2bf(A0.w);                   \
        o[4] = (short)f2bf(A1.x); o[5] = (short)f2bf(A1.y);                   \
        o[6] = (short)f2bf(A1.z); o[7] = (short)f2bf(A1.w);                   \
        *(bf16x8*)(As + srow * 40 + scol) = o;                                \
        o[0] = (short)f2bf(A2.x); o[1] = (short)f2bf(A2.y);                   \
        o[2] = (short)f2bf(A2.z); o[3] = (short)f2bf(A2.w);                   \
        o[4] = (short)f2bf(A3.x); o[5] = (short)f2bf(A3.y);                   \
        o[6] = (short)f2bf(A3.z); o[7] = (short)f2bf(A3.w);                   \
        *(bf16x8*)(As + (64 + srow) * 40 + scol) = o;                         \
    }

#define STOREB(kk)                                                            \
    {                                                                         \
        *(bf16x8*)(Bs + srow * 40 + scol) =                                   \
            *(const bf16x8*)(WT + (long)(n0 + srow) * EP + (kk) * 32 + scol); \
        *(bf16x8*)(Bs + (64 + srow) * 40 + scol) =                            \
            *(const bf16x8*)(WT + (long)(n0 + 64 + srow) * EP + (kk) * 32 + scol); \
    }

#define COMPUTE()                                                             \
    {                                                                         \
        bf16x8 af[4], bfr[4];                                                 \
        _Pragma("unroll")                                                     \
        for (int mf = 0; mf < 4; ++mf)                                        \
            af[mf] = *(const bf16x8*)(As + (wm + mf * 16 + lr) * 40 + lc * 8);\
        _Pragma("unroll")                                                     \
        for (int nf = 0; nf < 4; ++nf)                                        \
            bfr[nf] = *(const bf16x8*)(Bs + (wn + nf * 16 + lr) * 40 + lc * 8);\
        _Pragma("unroll")                                                     \
        for (int mf = 0; mf < 4; ++mf)                                        \
            _Pragma("unroll")                                                 \
            for (int nf = 0; nf < 4; ++nf)                                    \
                acc[mf][nf] = MFMA(af[mf], bfr[nf], acc[mf][nf]);             \
    }

    float4 x0, x1, x2, x3, y0, y1, y2, y3;
    GATHER(0, x0, x1, x2, x3);
    #pragma unroll
    for (int kk = 0; kk < 10; kk += 2) {
        __syncthreads();                             // LDS free (prev reads done)
        STOREA(x0, x1, x2, x3);
        STOREB(kk);
        GATHER(kk + 1, y0, y1, y2, y3);              // in flight during COMPUTE
        __syncthreads();
        COMPUTE();                                   // step kk
        __syncthreads();
        STOREA(y0, y1, y2, y3);
        STOREB(kk + 1);
        if (kk + 2 < 10) GATHER(kk + 2, x0, x1, x2, x3);
        __syncthreads();
        COMPUTE();                                   // step kk+1
    }
#undef GATHER
#undef STOREA
#undef STOREB
#undef COMPUTE

    // Epilogue: two 64-row phases through et[64][130] (aliased onto As/Bs)
    const int b = r0 >> 8, k0 = r0 & 255;
    #pragma unroll
    for (int ph = 0; ph < 2; ++ph) {
        __syncthreads();                             // K-loop / prev phase reads done
        if (wm == ph * 64) {
            #pragma unroll
            for (int mf = 0; mf < 4; ++mf)
            #pragma unroll
            for (int nf = 0; nf < 4; ++nf) {
                const int col = wn + nf * 16 + lr;
                const float bv = bias[n0 + col];
                #pragma unroll
                for (int r = 0; r < 4; ++r)
                    lds[(mf * 16 + lc * 4 + r) * 130 + col] =
                        f2bf(acc[mf][nf][r] + bv);
            }
        }
        __syncthreads();
        for (int i = t; i < 64 * 16; i += 256) {     // 64 rows x 16 chunks(16B)
            int k = i >> 4, c = i & 15;
            *(bf16x8*)(outr + (long)(r0 + ph * 64 + k) * H + n0 + c * 8) =
                *(const bf16x8*)(lds + k * 130 + c * 8);
        }
        if (!isq) {
            for (int i = t; i < 128 * 8; i += 256) { // 128 d x 8 chunks(16B)
                int d = i >> 3, c = i & 7;
                ushort tmp[8];
                #pragma unroll
                for (int j = 0; j < 8; ++j) tmp[j] = lds[(c * 8 + j) * 130 + d];
                *(bf16x8*)(hkT + (long)b * (H * NK) + (n0 + d) * NK +
                           k0 + ph * 64 + c * 8) = *(const bf16x8*)(tmp);
            }
        }
    }
}

// ---------------------------------------------------------------------------
// P2+P3 fused: att[b,g,q,k] = softmax_joint( (hq*watt_g) @ hk^T + batt[g] )
//     block=(b,g), 512 thr / 8 waves, BK=64 LDS-staged; A scaled during stage
// ---------------------------------------------------------------------------
__global__ __launch_bounds__(512) void attn_mfma(
    const ushort* __restrict__ hq, const ushort* __restrict__ hk,
    const float* __restrict__ watt, const float* __restrict__ batt,
    ushort* __restrict__ att)
{
    const int b = blockIdx.x, g = blockIdx.y;
    const int t = threadIdx.x, w = t >> 6, l = t & 63, lr = l & 15, lc = l >> 4;
    __shared__ float wg[H];                          //  4 KB
    __shared__ ushort As[32 * 72];                   //  4.6 KB
    __shared__ ushort Bs[256 * 72];                  // 36.9 KB
    __shared__ float red[16];

    for (int i = t; i < H; i += 512) wg[i] = watt[i * G + g];

    f32x4 acc[2][2] = {};
    __syncthreads();                                 // wg ready

    for (int kk = 0; kk < 16; ++kk) {                // BK=64
        if (kk) __syncthreads();                     // prev reads done
        if (t < 256) {                               // A: 32 x 64, scale on stage
            int r = t >> 3, c8 = (t & 7) * 8;
            bf16x8 hv = *(const bf16x8*)(hq + (b * NQ + r) * H + kk * 64 + c8);
            bf16x8 o;
            #pragma unroll
            for (int j = 0; j < 8; ++j)
                o[j] = (short)f2bf(bf2f((ushort)hv[j]) * wg[kk * 64 + c8 + j]);
            *(bf16x8*)(As + r * 72 + c8) = o;
        }
        #pragma unroll
        for (int p = 0; p < 4; ++p) {                // B: 256 x 64 coalesced
            int j = t + 512 * p;
            int r = j >> 3, c8 = (j & 7) * 8;
            *(bf16x8*)(Bs + r * 72 + c8) =
                *(const bf16x8*)(hk + (b * NK + r) * H + kk * 64 + c8);
        }
        __syncthreads();

        #pragma unroll
        for (int ks = 0; ks < 2; ++ks) {
            bf16x8 a0 = *(const bf16x8*)(As + lr * 72 + ks * 32 + lc * 8);
            bf16x8 a1 = *(const bf16x8*)(As + (16 + lr) * 72 + ks * 32 + lc * 8);
            bf16x8 b0 = *(const bf16x8*)(Bs + (w * 32 + lr) * 72 + ks * 32 + lc * 8);
            bf16x8 b1 = *(const bf16x8*)(Bs + (w * 32 + 16 + lr) * 72 + ks * 32 + lc * 8);
            acc[0][0] = MFMA(a0, b0, acc[0][0]);
            acc[0][1] = MFMA(a0, b1, acc[0][1]);
            acc[1][0] = MFMA(a1, b0, acc[1][0]);
            acc[1][1] = MFMA(a1, b1, acc[1][1]);
        }
    }

    const float bg = batt[g];
    float lm = -1e30f;
    #pragma unroll
    for (int mt = 0; mt < 2; ++mt)
    #pragma unroll
    for (int nf = 0; nf < 2; ++nf)
    #pragma unroll
    for (int r = 0; r < 4; ++r) {
        acc[mt][nf][r] += bg;
        lm = fmaxf(lm, acc[mt][nf][r]);
    }
    #pragma unroll
    for (int off = 32; off; off >>= 1) lm = fmaxf(lm, __shfl_xor(lm, off));
    if (l == 0) red[w] = lm;
    __syncthreads();
    float gm = red[0];
    #pragma unroll
    for (int i = 1; i < 8; ++i) gm = fmaxf(gm, red[i]);

    float ls = 0.f;
    #pragma unroll
    for (int mt = 0; mt < 2; ++mt)
    #pragma unroll
    for (int nf = 0; nf < 2; ++nf)
    #pragma unroll
    for (int r = 0; r < 4; ++r) {
        float e = __expf(acc[mt][nf][r] - gm);
        acc[mt][nf][r] = e;
        ls += e;
    }
    #pragma unroll
    for (int off = 32; off; off >>= 1) ls += __shfl_xor(ls, off);
    if (l == 0) red[8 + w] = ls;
    __syncthreads();
    float sum = red[8];
    #pragma unroll
    for (int i = 9; i < 16; ++i) sum += red[i];
    const float inv = 1.f / sum;

    ushort* op = att + (b * 8 + g) * (NQ * NK);
    #pragma unroll
    for (int mt = 0; mt < 2; ++mt)
    #pragma unroll
    for (int nf = 0; nf < 2; ++nf)
    #pragma unroll
    for (int r = 0; r < 4; ++r)
        op[(mt * 16 + lc * 4 + r) * NK + w * 32 + nf * 16 + lr] =
            f2bf(acc[mt][nf][r] * inv);
}

// ---------------------------------------------------------------------------
// P4: pooled as GEMM: ctx[gq, d] = att[b] (256x256) @ hkT[b] (1024d x 256k),
//     q-fold in-register; grid (64 b, 2 mt, 8 nt) x 256
// ---------------------------------------------------------------------------
__global__ __launch_bounds__(256, 2) void pooled_big(
    const ushort* __restrict__ att, const ushort* __restrict__ hkT,
    const ushort* __restrict__ hq, ushort* __restrict__ pooled_bf)
{
    __shared__ ushort lds[128 * 80];                 // As[128][40] + Bs[128][40]
    const int b = blockIdx.x, mt = blockIdx.y, nt = blockIdx.z;
    const int t = threadIdx.x;
    const int w = t >> 6, l = t & 63, lr = l & 15, lc = l >> 4;
    const int wm = (w >> 1) * 64, wn = (w & 1) * 64;
    const int srow = t >> 2;                         // staging row (64/pass)
    const int scol = (t & 3) * 8;
    ushort* As = lds;                                // [128][40]  att tile
    ushort* Bs = lds + 5120;                         // [128][40]  hkT tile
    const ushort* ab = att + (long)b * (G * NQ * NK) + (long)mt * 128 * NK;
    const ushort* bb = hkT + (long)b * (H * NK) + (long)nt * 128 * NK;
    f32x4 acc[4][4] = {};

    for (int kk = 0; kk < 8; ++kk) {                 // K=256, BK=32
        if (kk) __syncthreads();
        #pragma unroll
        for (int p = 0; p < 2; ++p) {
            int r = p * 64 + srow;
            *(bf16x8*)(As + r * 40 + scol) =
                *(const bf16x8*)(ab + (long)r * NK + kk * 32 + scol);
            *(bf16x8*)(Bs + r * 40 + scol) =
                *(const bf16x8*)(bb + (long)r * NK + kk * 32 + scol);
        }
        __syncthreads();

        bf16x8 af[4], bf[4];
        #pragma unroll
        for (int mf = 0; mf < 4; ++mf)
            af[mf] = *(const bf16x8*)(As + (wm + mf * 16 + lr) * 40 + lc * 8);
        #pragma unroll
        for (int nf = 0; nf < 4; ++nf)
            bf[nf] = *(const bf16x8*)(Bs + (wn + nf * 16 + lr) * 40 + lc * 8);
        #pragma unroll
        for (int mf = 0; mf < 4; ++mf)
            #pragma unroll
            for (int nf = 0; nf < 4; ++nf)
                acc[mf][nf] = MFMA(af[mf], bf[nf], acc[mf][nf]);
    }
    __syncthreads();                                 // loop reads done

    // stage hq tile [32 q][128 d] (cols nt*128..) pitch 136
    for (int i = t; i < 32 * 16; i += 256) {
        int r = i >> 4, c8 = (i & 15) * 8;
        *(bf16x8*)(lds + r * 136 + c8) =
            *(const bf16x8*)(hq + ((long)b * NQ + r) * H + nt * 128 + c8);
    }
    __syncthreads();

    // in-register q-fold: wave's 64 rows = 2 g-groups (gl = mf>>1)
    float s[2][4] = {};
    #pragma unroll
    for (int nf = 0; nf < 4; ++nf) {
        const int col = wn + nf * 16 + lr;           // tile col 0..127
        #pragma unroll
        for (int mf = 0; mf < 4; ++mf) {
            #pragma unroll
            for (int r = 0; r < 4; ++r) {
                const int q = (wm + mf * 16 + lc * 4 + r) & 31;
                s[mf >> 1][nf] += acc[mf][nf][r] * bf2f(lds[q * 136 + col]);
            }
        }
    }
    #pragma unroll
    for (int gl = 0; gl < 2; ++gl)
    #pragma unroll
    for (int nf = 0; nf < 4; ++nf) {
        float v = s[gl][nf];
        v += __shfl_xor(v, 16);
        v += __shfl_xor(v, 32);
        if (l < 16) {
            const int g = mt * 4 + (wm >> 5) + gl;   // wm/32 in {0,2}
            const int d = nt * 128 + wn + nf * 16 + lr;
            pooled_bf[((long)b * G + g) * H + d] = f2bf(v);
        }
    }
}

// ---------------------------------------------------------------------------
// P5: out = pooled_bf[64,8192] @ woutT^T  (MFMA, 64-way k-split)
// ---------------------------------------------------------------------------
__global__ __launch_bounds__(256) void outproj_mfma(
    const ushort* __restrict__ pooled_bf, const ushort* __restrict__ woutT,
    float* __restrict__ partial)
{
    const int ks = blockIdx.x;
    const int k0 = ks * 128;
    const int t = threadIdx.x, w = t >> 6, l = t & 63, lr = l & 15, lc = l >> 4;
    const ushort* ap = pooled_bf + lr * KOUT + k0 + lc * 8;
    const ushort* bp = woutT + (w * 80 + lr) * KOUT + k0 + lc * 8;
    f32x4 acc[4][5] = {};

    #pragma unroll
    for (int kk = 0; kk < 4; ++kk) {
        bf16x8 a[4];
        #pragma unroll
        for (int mt = 0; mt < 4; ++mt)
            a[mt] = *(const bf16x8*)(ap + mt * 16 * KOUT + kk * 32);
        #pragma unroll
        for (int nt = 0; nt < 5; ++nt) {
            bf16x8 bfr = *(const bf16x8*)(bp + nt * 16 * KOUT + kk * 32);
            #pragma unroll
            for (int mt = 0; mt < 4; ++mt)
                acc[mt][nt] = MFMA(a[mt], bfr, acc[mt][nt]);
        }
    }

    #pragma unroll
    for (int mt = 0; mt < 4; ++mt)
    #pragma unroll
    for (int nt = 0; nt < 5; ++nt)
    #pragma unroll
    for (int r = 0; r < 4; ++r) {
        const int bb = mt * 16 + lc * 4 + r;
        const int n = w * 80 + nt * 16 + lr;
        partial[(ks * B + bb) * NP + n] = acc[mt][nt][r];
    }
}

// ---------------------------------------------------------------------------
// P6: outv[b,n] = bout[n] + sum_ks partial[ks,b,n]   (76 blocks x 256)
// ---------------------------------------------------------------------------
__global__ __launch_bounds__(256) void reduce_out_kernel(
    const float* __restrict__ partial, const float* __restrict__ bout,
    float* __restrict__ outv)
{
    const int i = blockIdx.x * 256 + threadIdx.x;   // 64*304
    if (i >= B * 304) return;
    const int b = i / 304, n = i % 304;
    float acc = 0.f;
    if (n < NOUT) {
        acc = bout[n];
        for (int ks = 0; ks < 64; ++ks)
            acc += partial[(ks * B + b) * NP + n];
    }
    outv[b * 304 + n] = acc;
}

// ---------------------------------------------------------------------------
// S1: sim[b,a] = outv[b]·glove[a]  — 250 blocks x (16 answers x 64 b)
// ---------------------------------------------------------------------------
__global__ __launch_bounds__(256) void sim_kernel(
    const float* __restrict__ outv, const float* __restrict__ glove,
    float* __restrict__ sim)
{
    __shared__ __align__(16) float ov[64][308];
    __shared__ __align__(16) float gl[16][308];
    const int t = threadIdx.x;
    const int a0 = blockIdx.x * 16;

    for (int i = t; i < 64 * 75; i += 256) {
        int r = i / 75, c = i % 75;
        *(float4*)(&ov[r][c * 4]) = *(const float4*)(&outv[r * 304 + c * 4]);
    }
    for (int i = t; i < 16 * 75; i += 256) {
        int r = i / 75, c = i % 75;
        *(float4*)(&gl[r][c * 4]) = *(const float4*)(&glove[(a0 + r) * NOUT + c * 4]);
    }
    __syncthreads();

    const int a = t & 15, bg = t >> 4;   // 16 answers x 16 b-groups(4 b each)
    float acc[4] = {};
    for (int k4 = 0; k4 < 75; ++k4) {
        float4 g = *(const float4*)(&gl[a][k4 * 4]);
        #pragma unroll
        for (int bi = 0; bi < 4; ++bi) {
            float4 o = *(const float4*)(&ov[bg * 4 + bi][k4 * 4]);
            acc[bi] += g.x * o.x + g.y * o.y + g.z * o.z + g.w * o.w;
        }
    }
    #pragma unroll
    for (int bi = 0; bi < 4; ++bi)
        sim[(bg * 4 + bi) * NANS + a0 + a] = acc[bi];
}

// ---------------------------------------------------------------------------
// S2: per-b log_softmax over 4000, write d_out
// ---------------------------------------------------------------------------
__global__ __launch_bounds__(256) void lsm_kernel(
    const float* __restrict__ sim, float* __restrict__ dout)
{
    const int b = blockIdx.x, t = threadIdx.x;
    const float* p = sim + b * NANS;
    __shared__ float red[4];

    float4 v[4];
    float lm = -1e30f;
    #pragma unroll
    for (int j = 0; j < 4; ++j) {
        int i = t + j * 256;
        if (i < 1000) {
            v[j] = ((const float4*)p)[i];
            lm = fmaxf(lm, fmaxf(fmaxf(v[j].x, v[j].y), fmaxf(v[j].z, v[j].w)));
        }
    }
    #pragma unroll
    for (int off = 32; off; off >>= 1) lm = fmaxf(lm, __shfl_xor(lm, off));
    if ((t & 63) == 0) red[t >> 6] = lm;
    __syncthreads();
    const float gm = fmaxf(fmaxf(red[0], red[1]), fmaxf(red[2], red[3]));

    float ls = 0.f;
    #pragma unroll
    for (int j = 0; j < 4; ++j) {
        int i = t + j * 256;
        if (i < 1000)
            ls += __expf(v[j].x - gm) + __expf(v[j].y - gm) +
                  __expf(v[j].z - gm) + __expf(v[j].w - gm);
    }
    #pragma unroll
    for (int off = 32; off; off >>= 1) ls += __shfl_xor(ls, off);
    __syncthreads();
    if ((t & 63) == 0) red[t >> 6] = ls;
    __syncthreads();
    const float sh = gm + logf(red[0] + red[1] + red[2] + red[3]);

    #pragma unroll
    for (int j = 0; j < 4; ++j) {
        int i = t + j * 256;
        if (i < 1000) {
            float4 o;
            o.x = v[j].x - sh; o.y = v[j].y - sh;
            o.z = v[j].z - sh; o.w = v[j].w - sh;
            ((float4*)(dout + b * NANS))[i] = o;
        }
    }
}

// ---------------------------------------------------------------------------
extern "C" void kernel_launch(void* const* d_in, const int* in_sizes, int n_in,
                              void* d_out, int out_size, void* d_ws, size_t ws_size,
                              hipStream_t stream)
{
    (void)in_sizes; (void)n_in; (void)out_size; (void)ws_size;
    const int*   he_q  = (const int*)  d_in[0];
    const int*   he_k  = (const int*)  d_in[1];
    const float* emb   = (const float*)d_in[2];
    const float* Wq    = (const float*)d_in[3];
    const float* bq    = (const float*)d_in[4];
    const float* Wk    = (const float*)d_in[5];
    const float* bk    = (const float*)d_in[6];
    const float* Watt  = (const float*)d_in[7];
    const float* batt  = (const float*)d_in[8];
    const float* Wout  = (const float*)d_in[9];
    const float* bout  = (const float*)d_in[10];
    const float* glove = (const float*)d_in[11];
    float* out = (float*)d_out;

    ushort* WTq    = (ushort*)d_ws;                  //    327,680 sh
    ushort* WTk    = WTq + 327680;                   //    327,680 sh
    ushort* hq_bf  = WTk + 327680;                   //  2,097,152 sh  [b][q][d]
    ushort* hk_bf  = hq_bf + 2097152;                // 16,777,216 sh  [b][k][d]
    ushort* hkT    = hk_bf + 16777216;               // 16,777,216 sh  [b][d][k]
    ushort* pool_bf= hkT + 16777216;                 //    524,288 sh  [b][g*H+d]
    ushort* woutT  = pool_bf + 524288;               //  2,621,440 sh  [320][8192]
    ushort* att    = woutT + 2621440;                //  4,194,304 sh
    float*  partial= (float*)(att + 4194304);        //  1,310,720 f32 [64][64][320]
    float*  outv   = partial + 1310720;              //     19,456 f32
    float*  sim    = outv + 19456;                   //    256,000 f32

    prep_weights<<<dim3(800), 256, 0, stream>>>(Wq, Wk, Wout, WTq, WTk, woutT);
    proj_all<<<dim3(144, 8), 256, 0, stream>>>(he_q, he_k, emb, WTq, WTk,
                                               bq, bk, hq_bf, hk_bf, hkT);
    attn_mfma<<<dim3(64, 8), 512, 0, stream>>>(hq_bf, hk_bf, Watt, batt, att);
    pooled_big<<<dim3(64, 2, 8), 256, 0, stream>>>(att, hkT, hq_bf, pool_bf);
    outproj_mfma<<<dim3(64), 256, 0, stream>>>(pool_bf, woutT, partial);
    reduce_out_kernel<<<dim3(76), 256, 0, stream>>>(partial, bout, outv);
    sim_kernel<<<dim3(250), 256, 0, stream>>>(outv, glove, sim);
    lsm_kernel<<<dim3(64), 256, 0, stream>>>(sim, out);
}

// Round 17
// 128.665 us; speedup vs baseline: 1.0492x; 1.0492x over previous
//
#include <hip/hip_runtime.h>
#include <math.h>

#define VOCAB 20000
#define E     300
#define EP    320          // padded K for proj GEMM (10 k-steps of 32)
#define AGP   328          // a_gat row pitch (656B, 16B-aligned)
#define H     1024
#define G     8
#define NOUT  300
#define NP    320          // padded N for outproj
#define KOUT  8192         // G*H
#define NANS  4000
#define B     64
#define NQ    32
#define NK    256

typedef __attribute__((ext_vector_type(8))) short bf16x8;
typedef __attribute__((ext_vector_type(4))) float f32x4;

__device__ inline ushort f2bf(float x) {
    union { float f; unsigned u; } c; c.f = x;
    unsigned r = c.u + 0x7FFF + ((c.u >> 16) & 1);   // RNE
    return (ushort)(r >> 16);
}
__device__ inline float bf2f(ushort x) {
    union { unsigned u; float f; } c; c.u = ((unsigned)x) << 16;
    return c.f;
}
#define MFMA(a, b, c) __builtin_amdgcn_mfma_f32_16x16x32_bf16((a), (b), (c), 0, 0, 0)

// ---------------------------------------------------------------------------
// G0: a_gat[r][328] bf16 = emb[idx[r]][0:320padded]; q rows 0..2047, k after.
//     grid 1152 x 256 (16 rows/block) — pure streaming gather, high TLP
// ---------------------------------------------------------------------------
__global__ __launch_bounds__(256) void gather_all(
    const int* __restrict__ he_q, const int* __restrict__ he_k,
    const float* __restrict__ emb, ushort* __restrict__ a_gat)
{
    const int r0 = blockIdx.x * 16;                  // 0..18431
    for (int i = threadIdx.x; i < 16 * 80; i += 256) {
        int r = r0 + (i / 80), c4 = (i % 80) * 4;
        int row = (r < 2048) ? he_q[r] : he_k[r - 2048];
        ushort4 o{0, 0, 0, 0};
        if (c4 + 4 <= E) {
            float4 v = *(const float4*)(emb + (long)row * E + c4);
            o.x = f2bf(v.x); o.y = f2bf(v.y); o.z = f2bf(v.z); o.w = f2bf(v.w);
        }
        *(ushort4*)(a_gat + (long)r * AGP + c4) = o;
    }
}

// ---------------------------------------------------------------------------
// P0: merged weight prep. 800 blocks:
//   id <  160: WT[h][e] tiles from Wq/Wk (64h x 64e, f32 LDS bounce)
//   id >= 160: woutT[n][k] tiles from Wout (64k x 64n)
// ---------------------------------------------------------------------------
__global__ __launch_bounds__(256) void prep_weights(
    const float* __restrict__ Wq, const float* __restrict__ Wk,
    const float* __restrict__ Wout,
    ushort* __restrict__ WTq, ushort* __restrict__ WTk,
    ushort* __restrict__ woutT)
{
    __shared__ __align__(16) float lf[64 * 65];      // 16,640 B (aliased)
    const int id = blockIdx.x;
    const int t = threadIdx.x;

    if (id < 160) {
        const int hT = id % 16, eT = (id / 16) % 5, z = id / 80;
        const float* W = z ? Wk : Wq;
        ushort* WT = z ? WTk : WTq;
        const int h0 = hT * 64, e0 = eT * 64;

        for (int i = t; i < 64 * 64; i += 256) {     // coalesced along h
            int ec = i >> 6, hh = i & 63;
            int e = e0 + ec;
            lf[hh * 65 + ec] = (e < E) ? W[(long)e * H + h0 + hh] : 0.f;
        }
        __syncthreads();
        for (int i = t; i < 64 * 16; i += 256) {     // contiguous along e
            int hh = i >> 4, c = i & 15;
            ushort4 o;
            o.x = f2bf(lf[hh * 65 + c * 4 + 0]);
            o.y = f2bf(lf[hh * 65 + c * 4 + 1]);
            o.z = f2bf(lf[hh * 65 + c * 4 + 2]);
            o.w = f2bf(lf[hh * 65 + c * 4 + 3]);
            *(ushort4*)(WT + (long)(h0 + hh) * EP + e0 + c * 4) = o;
        }
    } else {
        ushort* td = (ushort*)lf;                    // [64][72]
        const int wid = id - 160;
        const int k0 = (wid & 127) * 64, n0 = (wid >> 7) * 64;
        for (int i = t; i < 64 * 64; i += 256) {
            int kk = i >> 6, nn = i & 63;
            int n = n0 + nn;
            float v = (n < NOUT) ? Wout[(long)(k0 + kk) * NOUT + n] : 0.f;
            td[nn * 72 + kk] = f2bf(v);
        }
        __syncthreads();
        for (int i = t; i < 64 * 8; i += 256) {
            int nn = i >> 3, c = i & 7;
            *(bf16x8*)(woutT + (long)(n0 + nn) * KOUT + k0 + c * 8) =
                *(const bf16x8*)(&td[nn * 72 + c * 8]);
        }
    }
}

// ---------------------------------------------------------------------------
// P1: merged GEMM for hq and hk from contiguous a_gat. grid (144, 8) x 256:
//   x < 16 : q-tiles (a_gat rows 0..2047  -> hq_bf)
//   x >= 16: k-tiles (a_gat rows 2048..   -> hk_bf + hkT)
// 128x128 tile, 4 waves, BK=32 x 10; two-phase 21KB epilogue
// ---------------------------------------------------------------------------
__global__ __launch_bounds__(256, 4) void proj_all(
    const ushort* __restrict__ a_gat,
    const ushort* __restrict__ WTq, const ushort* __restrict__ WTk,
    const float* __restrict__ bq, const float* __restrict__ bk,
    ushort* __restrict__ hq_bf, ushort* __restrict__ hk_bf,
    ushort* __restrict__ hkT)
{
    __shared__ ushort lds[10240];                    // 20,480 B (aliased)
    const bool isq = blockIdx.x < 16;
    const int xt = isq ? blockIdx.x : blockIdx.x - 16;
    const ushort* __restrict__ WT = isq ? WTq : WTk;
    const float* __restrict__ bias = isq ? bq : bk;
    ushort* __restrict__ outr = isq ? hq_bf : hk_bf;
    const int r0 = xt * 128;
    const int n0 = blockIdx.y * 128;
    const int t = threadIdx.x;
    const ushort* __restrict__ ag =
        a_gat + (isq ? 0L : 2048L * AGP) + (long)r0 * AGP;

    const int w = t >> 6, l = t & 63, lr = l & 15, lc = l >> 4;
    const int wm = (w >> 1) * 64, wn = (w & 1) * 64;
    const int srow = t >> 2;                         // staging row (64/pass)
    const int scol = (t & 3) * 8;                    // staging elem offset
    ushort* As = lds;                                // [128][40]
    ushort* Bs = lds + 5120;                         // [128][40]
    f32x4 acc[4][4] = {};

    for (int kk = 0; kk < 10; ++kk) {
        if (kk) __syncthreads();                     // prev reads done
        #pragma unroll
        for (int p = 0; p < 2; ++p) {
            int r = p * 64 + srow;
            *(bf16x8*)(As + r * 40 + scol) =
                *(const bf16x8*)(ag + (long)r * AGP + kk * 32 + scol);
            *(bf16x8*)(Bs + r * 40 + scol) =
                *(const bf16x8*)(WT + (long)(n0 + r) * EP + kk * 32 + scol);
        }
        __syncthreads();

        bf16x8 af[4], bf[4];
        #pragma unroll
        for (int mf = 0; mf < 4; ++mf)
            af[mf] = *(const bf16x8*)(As + (wm + mf * 16 + lr) * 40 + lc * 8);
        #pragma unroll
        for (int nf = 0; nf < 4; ++nf)
            bf[nf] = *(const bf16x8*)(Bs + (wn + nf * 16 + lr) * 40 + lc * 8);
        #pragma unroll
        for (int mf = 0; mf < 4; ++mf)
            #pragma unroll
            for (int nf = 0; nf < 4; ++nf)
                acc[mf][nf] = MFMA(af[mf], bf[nf], acc[mf][nf]);
    }

    // Epilogue: two 64-row phases through [64][130] (aliased onto As/Bs)
    const int b = r0 >> 8, k0 = r0 & 255;
    #pragma unroll
    for (int ph = 0; ph < 2; ++ph) {
        __syncthreads();                             // K-loop / prev phase reads done
        if (wm == ph * 64) {
            #pragma unroll
            for (int mf = 0; mf < 4; ++mf)
            #pragma unroll
            for (int nf = 0; nf < 4; ++nf) {
                const int col = wn + nf * 16 + lr;
                const float bv = bias[n0 + col];
                #pragma unroll
                for (int r = 0; r < 4; ++r)
                    lds[(mf * 16 + lc * 4 + r) * 130 + col] =
                        f2bf(acc[mf][nf][r] + bv);
            }
        }
        __syncthreads();
        for (int i = t; i < 64 * 16; i += 256) {     // 64 rows x 16 chunks(16B)
            int k = i >> 4, c = i & 15;
            *(bf16x8*)(outr + (long)(r0 + ph * 64 + k) * H + n0 + c * 8) =
                *(const bf16x8*)(lds + k * 130 + c * 8);
        }
        if (!isq) {
            for (int i = t; i < 128 * 8; i += 256) { // 128 d x 8 chunks(16B)
                int d = i >> 3, c = i & 7;
                ushort tmp[8];
                #pragma unroll
                for (int j = 0; j < 8; ++j) tmp[j] = lds[(c * 8 + j) * 130 + d];
                *(bf16x8*)(hkT + (long)b * (H * NK) + (n0 + d) * NK +
                           k0 + ph * 64 + c * 8) = *(const bf16x8*)(tmp);
            }
        }
    }
}

// ---------------------------------------------------------------------------
// P2+P3 fused: att[b,g,q,k] = softmax_joint( (hq*watt_g) @ hk^T + batt[g] )
//     block=(b,g), 512 thr / 8 waves, BK=64 LDS-staged; A scaled during stage
// ---------------------------------------------------------------------------
__global__ __launch_bounds__(512) void attn_mfma(
    const ushort* __restrict__ hq, const ushort* __restrict__ hk,
    const float* __restrict__ watt, const float* __restrict__ batt,
    ushort* __restrict__ att)
{
    const int b = blockIdx.x, g = blockIdx.y;
    const int t = threadIdx.x, w = t >> 6, l = t & 63, lr = l & 15, lc = l >> 4;
    __shared__ float wg[H];                          //  4 KB
    __shared__ ushort As[32 * 72];                   //  4.6 KB
    __shared__ ushort Bs[256 * 72];                  // 36.9 KB
    __shared__ float red[16];

    for (int i = t; i < H; i += 512) wg[i] = watt[i * G + g];

    f32x4 acc[2][2] = {};
    __syncthreads();                                 // wg ready

    for (int kk = 0; kk < 16; ++kk) {                // BK=64
        if (kk) __syncthreads();                     // prev reads done
        if (t < 256) {                               // A: 32 x 64, scale on stage
            int r = t >> 3, c8 = (t & 7) * 8;
            bf16x8 hv = *(const bf16x8*)(hq + (b * NQ + r) * H + kk * 64 + c8);
            bf16x8 o;
            #pragma unroll
            for (int j = 0; j < 8; ++j)
                o[j] = (short)f2bf(bf2f((ushort)hv[j]) * wg[kk * 64 + c8 + j]);
            *(bf16x8*)(As + r * 72 + c8) = o;
        }
        #pragma unroll
        for (int p = 0; p < 4; ++p) {                // B: 256 x 64 coalesced
            int j = t + 512 * p;
            int r = j >> 3, c8 = (j & 7) * 8;
            *(bf16x8*)(Bs + r * 72 + c8) =
                *(const bf16x8*)(hk + (b * NK + r) * H + kk * 64 + c8);
        }
        __syncthreads();

        #pragma unroll
        for (int ks = 0; ks < 2; ++ks) {
            bf16x8 a0 = *(const bf16x8*)(As + lr * 72 + ks * 32 + lc * 8);
            bf16x8 a1 = *(const bf16x8*)(As + (16 + lr) * 72 + ks * 32 + lc * 8);
            bf16x8 b0 = *(const bf16x8*)(Bs + (w * 32 + lr) * 72 + ks * 32 + lc * 8);
            bf16x8 b1 = *(const bf16x8*)(Bs + (w * 32 + 16 + lr) * 72 + ks * 32 + lc * 8);
            acc[0][0] = MFMA(a0, b0, acc[0][0]);
            acc[0][1] = MFMA(a0, b1, acc[0][1]);
            acc[1][0] = MFMA(a1, b0, acc[1][0]);
            acc[1][1] = MFMA(a1, b1, acc[1][1]);
        }
    }

    const float bg = batt[g];
    float lm = -1e30f;
    #pragma unroll
    for (int mt = 0; mt < 2; ++mt)
    #pragma unroll
    for (int nf = 0; nf < 2; ++nf)
    #pragma unroll
    for (int r = 0; r < 4; ++r) {
        acc[mt][nf][r] += bg;
        lm = fmaxf(lm, acc[mt][nf][r]);
    }
    #pragma unroll
    for (int off = 32; off; off >>= 1) lm = fmaxf(lm, __shfl_xor(lm, off));
    if (l == 0) red[w] = lm;
    __syncthreads();
    float gm = red[0];
    #pragma unroll
    for (int i = 1; i < 8; ++i) gm = fmaxf(gm, red[i]);

    float ls = 0.f;
    #pragma unroll
    for (int mt = 0; mt < 2; ++mt)
    #pragma unroll
    for (int nf = 0; nf < 2; ++nf)
    #pragma unroll
    for (int r = 0; r < 4; ++r) {
        float e = __expf(acc[mt][nf][r] - gm);
        acc[mt][nf][r] = e;
        ls += e;
    }
    #pragma unroll
    for (int off = 32; off; off >>= 1) ls += __shfl_xor(ls, off);
    if (l == 0) red[8 + w] = ls;
    __syncthreads();
    float sum = red[8];
    #pragma unroll
    for (int i = 9; i < 16; ++i) sum += red[i];
    const float inv = 1.f / sum;

    ushort* op = att + (b * 8 + g) * (NQ * NK);
    #pragma unroll
    for (int mt = 0; mt < 2; ++mt)
    #pragma unroll
    for (int nf = 0; nf < 2; ++nf)
    #pragma unroll
    for (int r = 0; r < 4; ++r)
        op[(mt * 16 + lc * 4 + r) * NK + w * 32 + nf * 16 + lr] =
            f2bf(acc[mt][nf][r] * inv);
}

// ---------------------------------------------------------------------------
// P4: pooled as GEMM: ctx[gq, d] = att[b] (256x256) @ hkT[b] (1024d x 256k),
//     q-fold in-register; grid (64 b, 2 mt, 8 nt) x 256
// ---------------------------------------------------------------------------
__global__ __launch_bounds__(256, 2) void pooled_big(
    const ushort* __restrict__ att, const ushort* __restrict__ hkT,
    const ushort* __restrict__ hq, ushort* __restrict__ pooled_bf)
{
    __shared__ ushort lds[128 * 80];                 // As[128][40] + Bs[128][40]
    const int b = blockIdx.x, mt = blockIdx.y, nt = blockIdx.z;
    const int t = threadIdx.x;
    const int w = t >> 6, l = t & 63, lr = l & 15, lc = l >> 4;
    const int wm = (w >> 1) * 64, wn = (w & 1) * 64;
    const int srow = t >> 2;                         // staging row (64/pass)
    const int scol = (t & 3) * 8;
    ushort* As = lds;                                // [128][40]  att tile
    ushort* Bs = lds + 5120;                         // [128][40]  hkT tile
    const ushort* ab = att + (long)b * (G * NQ * NK) + (long)mt * 128 * NK;
    const ushort* bb = hkT + (long)b * (H * NK) + (long)nt * 128 * NK;
    f32x4 acc[4][4] = {};

    for (int kk = 0; kk < 8; ++kk) {                 // K=256, BK=32
        if (kk) __syncthreads();
        #pragma unroll
        for (int p = 0; p < 2; ++p) {
            int r = p * 64 + srow;
            *(bf16x8*)(As + r * 40 + scol) =
                *(const bf16x8*)(ab + (long)r * NK + kk * 32 + scol);
            *(bf16x8*)(Bs + r * 40 + scol) =
                *(const bf16x8*)(bb + (long)r * NK + kk * 32 + scol);
        }
        __syncthreads();

        bf16x8 af[4], bf[4];
        #pragma unroll
        for (int mf = 0; mf < 4; ++mf)
            af[mf] = *(const bf16x8*)(As + (wm + mf * 16 + lr) * 40 + lc * 8);
        #pragma unroll
        for (int nf = 0; nf < 4; ++nf)
            bf[nf] = *(const bf16x8*)(Bs + (wn + nf * 16 + lr) * 40 + lc * 8);
        #pragma unroll
        for (int mf = 0; mf < 4; ++mf)
            #pragma unroll
            for (int nf = 0; nf < 4; ++nf)
                acc[mf][nf] = MFMA(af[mf], bf[nf], acc[mf][nf]);
    }
    __syncthreads();                                 // loop reads done

    // stage hq tile [32 q][128 d] (cols nt*128..) pitch 136
    for (int i = t; i < 32 * 16; i += 256) {
        int r = i >> 4, c8 = (i & 15) * 8;
        *(bf16x8*)(lds + r * 136 + c8) =
            *(const bf16x8*)(hq + ((long)b * NQ + r) * H + nt * 128 + c8);
    }
    __syncthreads();

    // in-register q-fold: wave's 64 rows = 2 g-groups (gl = mf>>1)
    float s[2][4] = {};
    #pragma unroll
    for (int nf = 0; nf < 4; ++nf) {
        const int col = wn + nf * 16 + lr;           // tile col 0..127
        #pragma unroll
        for (int mf = 0; mf < 4; ++mf) {
            #pragma unroll
            for (int r = 0; r < 4; ++r) {
                const int q = (wm + mf * 16 + lc * 4 + r) & 31;
                s[mf >> 1][nf] += acc[mf][nf][r] * bf2f(lds[q * 136 + col]);
            }
        }
    }
    #pragma unroll
    for (int gl = 0; gl < 2; ++gl)
    #pragma unroll
    for (int nf = 0; nf < 4; ++nf) {
        float v = s[gl][nf];
        v += __shfl_xor(v, 16);
        v += __shfl_xor(v, 32);
        if (l < 16) {
            const int g = mt * 4 + (wm >> 5) + gl;   // wm/32 in {0,2}
            const int d = nt * 128 + wn + nf * 16 + lr;
            pooled_bf[((long)b * G + g) * H + d] = f2bf(v);
        }
    }
}

// ---------------------------------------------------------------------------
// P5: out = pooled_bf[64,8192] @ woutT^T  (MFMA, 64-way k-split)
// ---------------------------------------------------------------------------
__global__ __launch_bounds__(256) void outproj_mfma(
    const ushort* __restrict__ pooled_bf, const ushort* __restrict__ woutT,
    float* __restrict__ partial)
{
    const int ks = blockIdx.x;
    const int k0 = ks * 128;
    const int t = threadIdx.x, w = t >> 6, l = t & 63, lr = l & 15, lc = l >> 4;
    const ushort* ap = pooled_bf + lr * KOUT + k0 + lc * 8;
    const ushort* bp = woutT + (w * 80 + lr) * KOUT + k0 + lc * 8;
    f32x4 acc[4][5] = {};

    #pragma unroll
    for (int kk = 0; kk < 4; ++kk) {
        bf16x8 a[4];
        #pragma unroll
        for (int mt = 0; mt < 4; ++mt)
            a[mt] = *(const bf16x8*)(ap + mt * 16 * KOUT + kk * 32);
        #pragma unroll
        for (int nt = 0; nt < 5; ++nt) {
            bf16x8 bfr = *(const bf16x8*)(bp + nt * 16 * KOUT + kk * 32);
            #pragma unroll
            for (int mt = 0; mt < 4; ++mt)
                acc[mt][nt] = MFMA(a[mt], bfr, acc[mt][nt]);
        }
    }

    #pragma unroll
    for (int mt = 0; mt < 4; ++mt)
    #pragma unroll
    for (int nt = 0; nt < 5; ++nt)
    #pragma unroll
    for (int r = 0; r < 4; ++r) {
        const int bb = mt * 16 + lc * 4 + r;
        const int n = w * 80 + nt * 16 + lr;
        partial[(ks * B + bb) * NP + n] = acc[mt][nt][r];
    }
}

// ---------------------------------------------------------------------------
// P6: outv[b,n] = bout[n] + sum_ks partial[ks,b,n]   (76 blocks x 256)
// ---------------------------------------------------------------------------
__global__ __launch_bounds__(256) void reduce_out_kernel(
    const float* __restrict__ partial, const float* __restrict__ bout,
    float* __restrict__ outv)
{
    const int i = blockIdx.x * 256 + threadIdx.x;   // 64*304
    if (i >= B * 304) return;
    const int b = i / 304, n = i % 304;
    float acc = 0.f;
    if (n < NOUT) {
        acc = bout[n];
        for (int ks = 0; ks < 64; ++ks)
            acc += partial[(ks * B + b) * NP + n];
    }
    outv[b * 304 + n] = acc;
}

// ---------------------------------------------------------------------------
// S1: sim[b,a] = outv[b]·glove[a]  — 250 blocks x (16 answers x 64 b)
// ---------------------------------------------------------------------------
__global__ __launch_bounds__(256) void sim_kernel(
    const float* __restrict__ outv, const float* __restrict__ glove,
    float* __restrict__ sim)
{
    __shared__ __align__(16) float ov[64][308];
    __shared__ __align__(16) float gl[16][308];
    const int t = threadIdx.x;
    const int a0 = blockIdx.x * 16;

    for (int i = t; i < 64 * 75; i += 256) {
        int r = i / 75, c = i % 75;
        *(float4*)(&ov[r][c * 4]) = *(const float4*)(&outv[r * 304 + c * 4]);
    }
    for (int i = t; i < 16 * 75; i += 256) {
        int r = i / 75, c = i % 75;
        *(float4*)(&gl[r][c * 4]) = *(const float4*)(&glove[(a0 + r) * NOUT + c * 4]);
    }
    __syncthreads();

    const int a = t & 15, bg = t >> 4;   // 16 answers x 16 b-groups(4 b each)
    float acc[4] = {};
    for (int k4 = 0; k4 < 75; ++k4) {
        float4 g = *(const float4*)(&gl[a][k4 * 4]);
        #pragma unroll
        for (int bi = 0; bi < 4; ++bi) {
            float4 o = *(const float4*)(&ov[bg * 4 + bi][k4 * 4]);
            acc[bi] += g.x * o.x + g.y * o.y + g.z * o.z + g.w * o.w;
        }
    }
    #pragma unroll
    for (int bi = 0; bi < 4; ++bi)
        sim[(bg * 4 + bi) * NANS + a0 + a] = acc[bi];
}

// ---------------------------------------------------------------------------
// S2: per-b log_softmax over 4000, write d_out
// ---------------------------------------------------------------------------
__global__ __launch_bounds__(256) void lsm_kernel(
    const float* __restrict__ sim, float* __restrict__ dout)
{
    const int b = blockIdx.x, t = threadIdx.x;
    const float* p = sim + b * NANS;
    __shared__ float red[4];

    float4 v[4];
    float lm = -1e30f;
    #pragma unroll
    for (int j = 0; j < 4; ++j) {
        int i = t + j * 256;
        if (i < 1000) {
            v[j] = ((const float4*)p)[i];
            lm = fmaxf(lm, fmaxf(fmaxf(v[j].x, v[j].y), fmaxf(v[j].z, v[j].w)));
        }
    }
    #pragma unroll
    for (int off = 32; off; off >>= 1) lm = fmaxf(lm, __shfl_xor(lm, off));
    if ((t & 63) == 0) red[t >> 6] = lm;
    __syncthreads();
    const float gm = fmaxf(fmaxf(red[0], red[1]), fmaxf(red[2], red[3]));

    float ls = 0.f;
    #pragma unroll
    for (int j = 0; j < 4; ++j) {
        int i = t + j * 256;
        if (i < 1000)
            ls += __expf(v[j].x - gm) + __expf(v[j].y - gm) +
                  __expf(v[j].z - gm) + __expf(v[j].w - gm);
    }
    #pragma unroll
    for (int off = 32; off; off >>= 1) ls += __shfl_xor(ls, off);
    __syncthreads();
    if ((t & 63) == 0) red[t >> 6] = ls;
    __syncthreads();
    const float sh = gm + logf(red[0] + red[1] + red[2] + red[3]);

    #pragma unroll
    for (int j = 0; j < 4; ++j) {
        int i = t + j * 256;
        if (i < 1000) {
            float4 o;
            o.x = v[j].x - sh; o.y = v[j].y - sh;
            o.z = v[j].z - sh; o.w = v[j].w - sh;
            ((float4*)(dout + b * NANS))[i] = o;
        }
    }
}

// ---------------------------------------------------------------------------
extern "C" void kernel_launch(void* const* d_in, const int* in_sizes, int n_in,
                              void* d_out, int out_size, void* d_ws, size_t ws_size,
                              hipStream_t stream)
{
    (void)in_sizes; (void)n_in; (void)out_size; (void)ws_size;
    const int*   he_q  = (const int*)  d_in[0];
    const int*   he_k  = (const int*)  d_in[1];
    const float* emb   = (const float*)d_in[2];
    const float* Wq    = (const float*)d_in[3];
    const float* bq    = (const float*)d_in[4];
    const float* Wk    = (const float*)d_in[5];
    const float* bk    = (const float*)d_in[6];
    const float* Watt  = (const float*)d_in[7];
    const float* batt  = (const float*)d_in[8];
    const float* Wout  = (const float*)d_in[9];
    const float* bout  = (const float*)d_in[10];
    const float* glove = (const float*)d_in[11];
    float* out = (float*)d_out;

    ushort* WTq    = (ushort*)d_ws;                  //    327,680 sh
    ushort* WTk    = WTq + 327680;                   //    327,680 sh
    ushort* a_gat  = WTk + 327680;                   //  6,045,696 sh  [18432][328]
    ushort* hq_bf  = a_gat + 6045696;                //  2,097,152 sh  [b][q][d]
    ushort* hk_bf  = hq_bf + 2097152;                // 16,777,216 sh  [b][k][d]
    ushort* hkT    = hk_bf + 16777216;               // 16,777,216 sh  [b][d][k]
    ushort* pool_bf= hkT + 16777216;                 //    524,288 sh  [b][g*H+d]
    ushort* woutT  = pool_bf + 524288;               //  2,621,440 sh  [320][8192]
    ushort* att    = woutT + 2621440;                //  4,194,304 sh
    float*  partial= (float*)(att + 4194304);        //  1,310,720 f32 [64][64][320]
    float*  outv   = partial + 1310720;              //     19,456 f32
    float*  sim    = outv + 19456;                   //    256,000 f32

    gather_all<<<dim3(1152), 256, 0, stream>>>(he_q, he_k, emb, a_gat);
    prep_weights<<<dim3(800), 256, 0, stream>>>(Wq, Wk, Wout, WTq, WTk, woutT);
    proj_all<<<dim3(144, 8), 256, 0, stream>>>(a_gat, WTq, WTk,
                                               bq, bk, hq_bf, hk_bf, hkT);
    attn_mfma<<<dim3(64, 8), 512, 0, stream>>>(hq_bf, hk_bf, Watt, batt, att);
    pooled_big<<<dim3(64, 2, 8), 256, 0, stream>>>(att, hkT, hq_bf, pool_bf);
    outproj_mfma<<<dim3(64), 256, 0, stream>>>(pool_bf, woutT, partial);
    reduce_out_kernel<<<dim3(76), 256, 0, stream>>>(partial, bout, outv);
    sim_kernel<<<dim3(250), 256, 0, stream>>>(outv, glove, sim);
    lsm_kernel<<<dim3(64), 256, 0, stream>>>(sim, out);
}

// Round 18
// 122.922 us; speedup vs baseline: 1.0983x; 1.0467x over previous
//
#include <hip/hip_runtime.h>
#include <math.h>

#define VOCAB 20000
#define E     300
#define EP    320          // padded K for proj GEMM (5 k-steps of 64)
#define AGP   328          // a_gat row pitch (656B, 16B-aligned)
#define H     1024
#define G     8
#define NOUT  300
#define NP    320          // padded N for outproj
#define KOUT  8192         // G*H
#define NANS  4000
#define B     64
#define NQ    32
#define NK    256

typedef __attribute__((ext_vector_type(8))) short bf16x8;
typedef __attribute__((ext_vector_type(4))) float f32x4;

__device__ inline ushort f2bf(float x) {
    union { float f; unsigned u; } c; c.f = x;
    unsigned r = c.u + 0x7FFF + ((c.u >> 16) & 1);   // RNE
    return (ushort)(r >> 16);
}
__device__ inline float bf2f(ushort x) {
    union { unsigned u; float f; } c; c.u = ((unsigned)x) << 16;
    return c.f;
}
#define MFMA(a, b, c) __builtin_amdgcn_mfma_f32_16x16x32_bf16((a), (b), (c), 0, 0, 0)

// ---------------------------------------------------------------------------
// G0: a_gat[r][328] bf16 = emb[idx[r]][0:320padded]; q rows 0..2047, k after.
// ---------------------------------------------------------------------------
__global__ __launch_bounds__(256) void gather_all(
    const int* __restrict__ he_q, const int* __restrict__ he_k,
    const float* __restrict__ emb, ushort* __restrict__ a_gat)
{
    const int r0 = blockIdx.x * 16;                  // 0..18431
    for (int i = threadIdx.x; i < 16 * 80; i += 256) {
        int r = r0 + (i / 80), c4 = (i % 80) * 4;
        int row = (r < 2048) ? he_q[r] : he_k[r - 2048];
        ushort4 o{0, 0, 0, 0};
        if (c4 + 4 <= E) {
            float4 v = *(const float4*)(emb + (long)row * E + c4);
            o.x = f2bf(v.x); o.y = f2bf(v.y); o.z = f2bf(v.z); o.w = f2bf(v.w);
        }
        *(ushort4*)(a_gat + (long)r * AGP + c4) = o;
    }
}

// ---------------------------------------------------------------------------
// P0: merged weight prep. 800 blocks.
// ---------------------------------------------------------------------------
__global__ __launch_bounds__(256) void prep_weights(
    const float* __restrict__ Wq, const float* __restrict__ Wk,
    const float* __restrict__ Wout,
    ushort* __restrict__ WTq, ushort* __restrict__ WTk,
    ushort* __restrict__ woutT)
{
    __shared__ __align__(16) float lf[64 * 65];      // 16,640 B (aliased)
    const int id = blockIdx.x;
    const int t = threadIdx.x;

    if (id < 160) {
        const int hT = id % 16, eT = (id / 16) % 5, z = id / 80;
        const float* W = z ? Wk : Wq;
        ushort* WT = z ? WTk : WTq;
        const int h0 = hT * 64, e0 = eT * 64;

        for (int i = t; i < 64 * 64; i += 256) {     // coalesced along h
            int ec = i >> 6, hh = i & 63;
            int e = e0 + ec;
            lf[hh * 65 + ec] = (e < E) ? W[(long)e * H + h0 + hh] : 0.f;
        }
        __syncthreads();
        for (int i = t; i < 64 * 16; i += 256) {     // contiguous along e
            int hh = i >> 4, c = i & 15;
            ushort4 o;
            o.x = f2bf(lf[hh * 65 + c * 4 + 0]);
            o.y = f2bf(lf[hh * 65 + c * 4 + 1]);
            o.z = f2bf(lf[hh * 65 + c * 4 + 2]);
            o.w = f2bf(lf[hh * 65 + c * 4 + 3]);
            *(ushort4*)(WT + (long)(h0 + hh) * EP + e0 + c * 4) = o;
        }
    } else {
        ushort* td = (ushort*)lf;                    // [64][72]
        const int wid = id - 160;
        const int k0 = (wid & 127) * 64, n0 = (wid >> 7) * 64;
        for (int i = t; i < 64 * 64; i += 256) {
            int kk = i >> 6, nn = i & 63;
            int n = n0 + nn;
            float v = (n < NOUT) ? Wout[(long)(k0 + kk) * NOUT + n] : 0.f;
            td[nn * 72 + kk] = f2bf(v);
        }
        __syncthreads();
        for (int i = t; i < 64 * 8; i += 256) {
            int nn = i >> 3, c = i & 7;
            *(bf16x8*)(woutT + (long)(n0 + nn) * KOUT + k0 + c * 8) =
                *(const bf16x8*)(&td[nn * 72 + c * 8]);
        }
    }
}

// ---------------------------------------------------------------------------
// P1: merged GEMM for hq and hk from contiguous a_gat. grid (144, 8) x 256:
// 128x128 tile, 4 waves, BK=64 x 5 steps (half the barriers of BK=32 x 10)
// ---------------------------------------------------------------------------
__global__ __launch_bounds__(256, 4) void proj_all(
    const ushort* __restrict__ a_gat,
    const ushort* __restrict__ WTq, const ushort* __restrict__ WTk,
    const float* __restrict__ bq, const float* __restrict__ bk,
    ushort* __restrict__ hq_bf, ushort* __restrict__ hk_bf,
    ushort* __restrict__ hkT)
{
    __shared__ ushort lds[2 * 128 * 72];             // 36,864 B (aliased)
    const bool isq = blockIdx.x < 16;
    const int xt = isq ? blockIdx.x : blockIdx.x - 16;
    const ushort* __restrict__ WT = isq ? WTq : WTk;
    const float* __restrict__ bias = isq ? bq : bk;
    ushort* __restrict__ outr = isq ? hq_bf : hk_bf;
    const int r0 = xt * 128;
    const int n0 = blockIdx.y * 128;
    const int t = threadIdx.x;
    const ushort* __restrict__ ag =
        a_gat + (isq ? 0L : 2048L * AGP) + (long)r0 * AGP;

    const int w = t >> 6, l = t & 63, lr = l & 15, lc = l >> 4;
    const int wm = (w >> 1) * 64, wn = (w & 1) * 64;
    const int srow = t >> 3;                         // 32 rows/pass
    const int scol = (t & 7) * 8;                    // 0..56
    ushort* As = lds;                                // [128][72]
    ushort* Bs = lds + 128 * 72;                     // [128][72]
    f32x4 acc[4][4] = {};

    for (int kk = 0; kk < 5; ++kk) {                 // BK=64
        if (kk) __syncthreads();                     // prev reads done
        #pragma unroll
        for (int p = 0; p < 4; ++p) {
            int r = p * 32 + srow;
            *(bf16x8*)(As + r * 72 + scol) =
                *(const bf16x8*)(ag + (long)r * AGP + kk * 64 + scol);
            *(bf16x8*)(Bs + r * 72 + scol) =
                *(const bf16x8*)(WT + (long)(n0 + r) * EP + kk * 64 + scol);
        }
        __syncthreads();

        #pragma unroll
        for (int ks = 0; ks < 2; ++ks) {
            bf16x8 af[4], bf[4];
            #pragma unroll
            for (int mf = 0; mf < 4; ++mf)
                af[mf] = *(const bf16x8*)(As + (wm + mf * 16 + lr) * 72 +
                                          ks * 32 + lc * 8);
            #pragma unroll
            for (int nf = 0; nf < 4; ++nf)
                bf[nf] = *(const bf16x8*)(Bs + (wn + nf * 16 + lr) * 72 +
                                          ks * 32 + lc * 8);
            #pragma unroll
            for (int mf = 0; mf < 4; ++mf)
                #pragma unroll
                for (int nf = 0; nf < 4; ++nf)
                    acc[mf][nf] = MFMA(af[mf], bf[nf], acc[mf][nf]);
        }
    }

    // Epilogue: two 64-row phases through [64][130] (aliased onto As/Bs)
    const int b = r0 >> 8, k0 = r0 & 255;
    #pragma unroll
    for (int ph = 0; ph < 2; ++ph) {
        __syncthreads();                             // K-loop / prev phase reads done
        if (wm == ph * 64) {
            #pragma unroll
            for (int mf = 0; mf < 4; ++mf)
            #pragma unroll
            for (int nf = 0; nf < 4; ++nf) {
                const int col = wn + nf * 16 + lr;
                const float bv = bias[n0 + col];
                #pragma unroll
                for (int r = 0; r < 4; ++r)
                    lds[(mf * 16 + lc * 4 + r) * 130 + col] =
                        f2bf(acc[mf][nf][r] + bv);
            }
        }
        __syncthreads();
        for (int i = t; i < 64 * 16; i += 256) {     // 64 rows x 16 chunks(16B)
            int k = i >> 4, c = i & 15;
            *(bf16x8*)(outr + (long)(r0 + ph * 64 + k) * H + n0 + c * 8) =
                *(const bf16x8*)(lds + k * 130 + c * 8);
        }
        if (!isq) {
            for (int i = t; i < 128 * 8; i += 256) { // 128 d x 8 chunks(16B)
                int d = i >> 3, c = i & 7;
                ushort tmp[8];
                #pragma unroll
                for (int j = 0; j < 8; ++j) tmp[j] = lds[(c * 8 + j) * 130 + d];
                *(bf16x8*)(hkT + (long)b * (H * NK) + (n0 + d) * NK +
                           k0 + ph * 64 + c * 8) = *(const bf16x8*)(tmp);
            }
        }
    }
}

// ---------------------------------------------------------------------------
// P2+P3 fused: att[b,g,q,k] = softmax_joint( (hq*watt_g) @ hk^T + batt[g] )
//     block=(b,g), 512 thr / 8 waves, BK=64 LDS-staged; A scaled during stage
// ---------------------------------------------------------------------------
__global__ __launch_bounds__(512) void attn_mfma(
    const ushort* __restrict__ hq, const ushort* __restrict__ hk,
    const float* __restrict__ watt, const float* __restrict__ batt,
    ushort* __restrict__ att)
{
    const int b = blockIdx.x, g = blockIdx.y;
    const int t = threadIdx.x, w = t >> 6, l = t & 63, lr = l & 15, lc = l >> 4;
    __shared__ float wg[H];                          //  4 KB
    __shared__ ushort As[32 * 72];                   //  4.6 KB
    __shared__ ushort Bs[256 * 72];                  // 36.9 KB
    __shared__ float red[16];

    for (int i = t; i < H; i += 512) wg[i] = watt[i * G + g];

    f32x4 acc[2][2] = {};
    __syncthreads();                                 // wg ready

    for (int kk = 0; kk < 16; ++kk) {                // BK=64
        if (kk) __syncthreads();                     // prev reads done
        if (t < 256) {                               // A: 32 x 64, scale on stage
            int r = t >> 3, c8 = (t & 7) * 8;
            bf16x8 hv = *(const bf16x8*)(hq + (b * NQ + r) * H + kk * 64 + c8);
            bf16x8 o;
            #pragma unroll
            for (int j = 0; j < 8; ++j)
                o[j] = (short)f2bf(bf2f((ushort)hv[j]) * wg[kk * 64 + c8 + j]);
            *(bf16x8*)(As + r * 72 + c8) = o;
        }
        #pragma unroll
        for (int p = 0; p < 4; ++p) {                // B: 256 x 64 coalesced
            int j = t + 512 * p;
            int r = j >> 3, c8 = (j & 7) * 8;
            *(bf16x8*)(Bs + r * 72 + c8) =
                *(const bf16x8*)(hk + (b * NK + r) * H + kk * 64 + c8);
        }
        __syncthreads();

        #pragma unroll
        for (int ks = 0; ks < 2; ++ks) {
            bf16x8 a0 = *(const bf16x8*)(As + lr * 72 + ks * 32 + lc * 8);
            bf16x8 a1 = *(const bf16x8*)(As + (16 + lr) * 72 + ks * 32 + lc * 8);
            bf16x8 b0 = *(const bf16x8*)(Bs + (w * 32 + lr) * 72 + ks * 32 + lc * 8);
            bf16x8 b1 = *(const bf16x8*)(Bs + (w * 32 + 16 + lr) * 72 + ks * 32 + lc * 8);
            acc[0][0] = MFMA(a0, b0, acc[0][0]);
            acc[0][1] = MFMA(a0, b1, acc[0][1]);
            acc[1][0] = MFMA(a1, b0, acc[1][0]);
            acc[1][1] = MFMA(a1, b1, acc[1][1]);
        }
    }

    const float bg = batt[g];
    float lm = -1e30f;
    #pragma unroll
    for (int mt = 0; mt < 2; ++mt)
    #pragma unroll
    for (int nf = 0; nf < 2; ++nf)
    #pragma unroll
    for (int r = 0; r < 4; ++r) {
        acc[mt][nf][r] += bg;
        lm = fmaxf(lm, acc[mt][nf][r]);
    }
    #pragma unroll
    for (int off = 32; off; off >>= 1) lm = fmaxf(lm, __shfl_xor(lm, off));
    if (l == 0) red[w] = lm;
    __syncthreads();
    float gm = red[0];
    #pragma unroll
    for (int i = 1; i < 8; ++i) gm = fmaxf(gm, red[i]);

    float ls = 0.f;
    #pragma unroll
    for (int mt = 0; mt < 2; ++mt)
    #pragma unroll
    for (int nf = 0; nf < 2; ++nf)
    #pragma unroll
    for (int r = 0; r < 4; ++r) {
        float e = __expf(acc[mt][nf][r] - gm);
        acc[mt][nf][r] = e;
        ls += e;
    }
    #pragma unroll
    for (int off = 32; off; off >>= 1) ls += __shfl_xor(ls, off);
    if (l == 0) red[8 + w] = ls;
    __syncthreads();
    float sum = red[8];
    #pragma unroll
    for (int i = 9; i < 16; ++i) sum += red[i];
    const float inv = 1.f / sum;

    ushort* op = att + (b * 8 + g) * (NQ * NK);
    #pragma unroll
    for (int mt = 0; mt < 2; ++mt)
    #pragma unroll
    for (int nf = 0; nf < 2; ++nf)
    #pragma unroll
    for (int r = 0; r < 4; ++r)
        op[(mt * 16 + lc * 4 + r) * NK + w * 32 + nf * 16 + lr] =
            f2bf(acc[mt][nf][r] * inv);
}

// ---------------------------------------------------------------------------
// P4: pooled as GEMM; BK=64 x 4 steps; q-fold in-register
//     grid (64 b, 2 mt, 8 nt) x 256
// ---------------------------------------------------------------------------
__global__ __launch_bounds__(256, 2) void pooled_big(
    const ushort* __restrict__ att, const ushort* __restrict__ hkT,
    const ushort* __restrict__ hq, ushort* __restrict__ pooled_bf)
{
    __shared__ ushort lds[2 * 128 * 72];             // 36,864 B (aliased)
    const int b = blockIdx.x, mt = blockIdx.y, nt = blockIdx.z;
    const int t = threadIdx.x;
    const int w = t >> 6, l = t & 63, lr = l & 15, lc = l >> 4;
    const int wm = (w >> 1) * 64, wn = (w & 1) * 64;
    const int srow = t >> 3;                         // 32 rows/pass
    const int scol = (t & 7) * 8;                    // 0..56
    ushort* As = lds;                                // [128][72]  att tile
    ushort* Bs = lds + 128 * 72;                     // [128][72]  hkT tile
    const ushort* ab = att + (long)b * (G * NQ * NK) + (long)mt * 128 * NK;
    const ushort* bb = hkT + (long)b * (H * NK) + (long)nt * 128 * NK;
    f32x4 acc[4][4] = {};

    for (int kk = 0; kk < 4; ++kk) {                 // K=256, BK=64
        if (kk) __syncthreads();
        #pragma unroll
        for (int p = 0; p < 4; ++p) {
            int r = p * 32 + srow;
            *(bf16x8*)(As + r * 72 + scol) =
                *(const bf16x8*)(ab + (long)r * NK + kk * 64 + scol);
            *(bf16x8*)(Bs + r * 72 + scol) =
                *(const bf16x8*)(bb + (long)r * NK + kk * 64 + scol);
        }
        __syncthreads();

        #pragma unroll
        for (int ks = 0; ks < 2; ++ks) {
            bf16x8 af[4], bf[4];
            #pragma unroll
            for (int mf = 0; mf < 4; ++mf)
                af[mf] = *(const bf16x8*)(As + (wm + mf * 16 + lr) * 72 +
                                          ks * 32 + lc * 8);
            #pragma unroll
            for (int nf = 0; nf < 4; ++nf)
                bf[nf] = *(const bf16x8*)(Bs + (wn + nf * 16 + lr) * 72 +
                                          ks * 32 + lc * 8);
            #pragma unroll
            for (int mf = 0; mf < 4; ++mf)
                #pragma unroll
                for (int nf = 0; nf < 4; ++nf)
                    acc[mf][nf] = MFMA(af[mf], bf[nf], acc[mf][nf]);
        }
    }
    __syncthreads();                                 // loop reads done

    // stage hq tile [32 q][128 d] (cols nt*128..) pitch 136
    for (int i = t; i < 32 * 16; i += 256) {
        int r = i >> 4, c8 = (i & 15) * 8;
        *(bf16x8*)(lds + r * 136 + c8) =
            *(const bf16x8*)(hq + ((long)b * NQ + r) * H + nt * 128 + c8);
    }
    __syncthreads();

    // in-register q-fold: wave's 64 rows = 2 g-groups (gl = mf>>1)
    float s[2][4] = {};
    #pragma unroll
    for (int nf = 0; nf < 4; ++nf) {
        const int col = wn + nf * 16 + lr;           // tile col 0..127
        #pragma unroll
        for (int mf = 0; mf < 4; ++mf) {
            #pragma unroll
            for (int r = 0; r < 4; ++r) {
                const int q = (wm + mf * 16 + lc * 4 + r) & 31;
                s[mf >> 1][nf] += acc[mf][nf][r] * bf2f(lds[q * 136 + col]);
            }
        }
    }
    #pragma unroll
    for (int gl = 0; gl < 2; ++gl)
    #pragma unroll
    for (int nf = 0; nf < 4; ++nf) {
        float v = s[gl][nf];
        v += __shfl_xor(v, 16);
        v += __shfl_xor(v, 32);
        if (l < 16) {
            const int g = mt * 4 + (wm >> 5) + gl;   // wm/32 in {0,2}
            const int d = nt * 128 + wn + nf * 16 + lr;
            pooled_bf[((long)b * G + g) * H + d] = f2bf(v);
        }
    }
}

// ---------------------------------------------------------------------------
// P5: out = pooled_bf[64,8192] @ woutT^T  (MFMA, 64-way k-split)
// ---------------------------------------------------------------------------
__global__ __launch_bounds__(256) void outproj_mfma(
    const ushort* __restrict__ pooled_bf, const ushort* __restrict__ woutT,
    float* __restrict__ partial)
{
    const int ks = blockIdx.x;
    const int k0 = ks * 128;
    const int t = threadIdx.x, w = t >> 6, l = t & 63, lr = l & 15, lc = l >> 4;
    const ushort* ap = pooled_bf + lr * KOUT + k0 + lc * 8;
    const ushort* bp = woutT + (w * 80 + lr) * KOUT + k0 + lc * 8;
    f32x4 acc[4][5] = {};

    #pragma unroll
    for (int kk = 0; kk < 4; ++kk) {
        bf16x8 a[4];
        #pragma unroll
        for (int mt = 0; mt < 4; ++mt)
            a[mt] = *(const bf16x8*)(ap + mt * 16 * KOUT + kk * 32);
        #pragma unroll
        for (int nt = 0; nt < 5; ++nt) {
            bf16x8 bfr = *(const bf16x8*)(bp + nt * 16 * KOUT + kk * 32);
            #pragma unroll
            for (int mt = 0; mt < 4; ++mt)
                acc[mt][nt] = MFMA(a[mt], bfr, acc[mt][nt]);
        }
    }

    #pragma unroll
    for (int mt = 0; mt < 4; ++mt)
    #pragma unroll
    for (int nt = 0; nt < 5; ++nt)
    #pragma unroll
    for (int r = 0; r < 4; ++r) {
        const int bb = mt * 16 + lc * 4 + r;
        const int n = w * 80 + nt * 16 + lr;
        partial[(ks * B + bb) * NP + n] = acc[mt][nt][r];
    }
}

// ---------------------------------------------------------------------------
// P6: outv[b,n] = bout[n] + sum_ks partial[ks,b,n]   (76 blocks x 256)
// ---------------------------------------------------------------------------
__global__ __launch_bounds__(256) void reduce_out_kernel(
    const float* __restrict__ partial, const float* __restrict__ bout,
    float* __restrict__ outv)
{
    const int i = blockIdx.x * 256 + threadIdx.x;   // 64*304
    if (i >= B * 304) return;
    const int b = i / 304, n = i % 304;
    float acc = 0.f;
    if (n < NOUT) {
        acc = bout[n];
        for (int ks = 0; ks < 64; ++ks)
            acc += partial[(ks * B + b) * NP + n];
    }
    outv[b * 304 + n] = acc;
}

// ---------------------------------------------------------------------------
// S1: sim[b,a] = outv[b]·glove[a]  — 250 blocks x (16 answers x 64 b)
// ---------------------------------------------------------------------------
__global__ __launch_bounds__(256) void sim_kernel(
    const float* __restrict__ outv, const float* __restrict__ glove,
    float* __restrict__ sim)
{
    __shared__ __align__(16) float ov[64][308];
    __shared__ __align__(16) float gl[16][308];
    const int t = threadIdx.x;
    const int a0 = blockIdx.x * 16;

    for (int i = t; i < 64 * 75; i += 256) {
        int r = i / 75, c = i % 75;
        *(float4*)(&ov[r][c * 4]) = *(const float4*)(&outv[r * 304 + c * 4]);
    }
    for (int i = t; i < 16 * 75; i += 256) {
        int r = i / 75, c = i % 75;
        *(float4*)(&gl[r][c * 4]) = *(const float4*)(&glove[(a0 + r) * NOUT + c * 4]);
    }
    __syncthreads();

    const int a = t & 15, bg = t >> 4;   // 16 answers x 16 b-groups(4 b each)
    float acc[4] = {};
    for (int k4 = 0; k4 < 75; ++k4) {
        float4 g = *(const float4*)(&gl[a][k4 * 4]);
        #pragma unroll
        for (int bi = 0; bi < 4; ++bi) {
            float4 o = *(const float4*)(&ov[bg * 4 + bi][k4 * 4]);
            acc[bi] += g.x * o.x + g.y * o.y + g.z * o.z + g.w * o.w;
        }
    }
    #pragma unroll
    for (int bi = 0; bi < 4; ++bi)
        sim[(bg * 4 + bi) * NANS + a0 + a] = acc[bi];
}

// ---------------------------------------------------------------------------
// S2: per-b log_softmax over 4000, write d_out
// ---------------------------------------------------------------------------
__global__ __launch_bounds__(256) void lsm_kernel(
    const float* __restrict__ sim, float* __restrict__ dout)
{
    const int b = blockIdx.x, t = threadIdx.x;
    const float* p = sim + b * NANS;
    __shared__ float red[4];

    float4 v[4];
    float lm = -1e30f;
    #pragma unroll
    for (int j = 0; j < 4; ++j) {
        int i = t + j * 256;
        if (i < 1000) {
            v[j] = ((const float4*)p)[i];
            lm = fmaxf(lm, fmaxf(fmaxf(v[j].x, v[j].y), fmaxf(v[j].z, v[j].w)));
        }
    }
    #pragma unroll
    for (int off = 32; off; off >>= 1) lm = fmaxf(lm, __shfl_xor(lm, off));
    if ((t & 63) == 0) red[t >> 6] = lm;
    __syncthreads();
    const float gm = fmaxf(fmaxf(red[0], red[1]), fmaxf(red[2], red[3]));

    float ls = 0.f;
    #pragma unroll
    for (int j = 0; j < 4; ++j) {
        int i = t + j * 256;
        if (i < 1000)
            ls += __expf(v[j].x - gm) + __expf(v[j].y - gm) +
                  __expf(v[j].z - gm) + __expf(v[j].w - gm);
    }
    #pragma unroll
    for (int off = 32; off; off >>= 1) ls += __shfl_xor(ls, off);
    __syncthreads();
    if ((t & 63) == 0) red[t >> 6] = ls;
    __syncthreads();
    const float sh = gm + logf(red[0] + red[1] + red[2] + red[3]);

    #pragma unroll
    for (int j = 0; j < 4; ++j) {
        int i = t + j * 256;
        if (i < 1000) {
            float4 o;
            o.x = v[j].x - sh; o.y = v[j].y - sh;
            o.z = v[j].z - sh; o.w = v[j].w - sh;
            ((float4*)(dout + b * NANS))[i] = o;
        }
    }
}

// ---------------------------------------------------------------------------
extern "C" void kernel_launch(void* const* d_in, const int* in_sizes, int n_in,
                              void* d_out, int out_size, void* d_ws, size_t ws_size,
                              hipStream_t stream)
{
    (void)in_sizes; (void)n_in; (void)out_size; (void)ws_size;
    const int*   he_q  = (const int*)  d_in[0];
    const int*   he_k  = (const int*)  d_in[1];
    const float* emb   = (const float*)d_in[2];
    const float* Wq    = (const float*)d_in[3];
    const float* bq    = (const float*)d_in[4];
    const float* Wk    = (const float*)d_in[5];
    const float* bk    = (const float*)d_in[6];
    const float* Watt  = (const float*)d_in[7];
    const float* batt  = (const float*)d_in[8];
    const float* Wout  = (const float*)d_in[9];
    const float* bout  = (const float*)d_in[10];
    const float* glove = (const float*)d_in[11];
    float* out = (float*)d_out;

    ushort* WTq    = (ushort*)d_ws;                  //    327,680 sh
    ushort* WTk    = WTq + 327680;                   //    327,680 sh
    ushort* a_gat  = WTk + 327680;                   //  6,045,696 sh  [18432][328]
    ushort* hq_bf  = a_gat + 6045696;                //  2,097,152 sh  [b][q][d]
    ushort* hk_bf  = hq_bf + 2097152;                // 16,777,216 sh  [b][k][d]
    ushort* hkT    = hk_bf + 16777216;               // 16,777,216 sh  [b][d][k]
    ushort* pool_bf= hkT + 16777216;                 //    524,288 sh  [b][g*H+d]
    ushort* woutT  = pool_bf + 524288;               //  2,621,440 sh  [320][8192]
    ushort* att    = woutT + 2621440;                //  4,194,304 sh
    float*  partial= (float*)(att + 4194304);        //  1,310,720 f32 [64][64][320]
    float*  outv   = partial + 1310720;              //     19,456 f32
    float*  sim    = outv + 19456;                   //    256,000 f32

    gather_all<<<dim3(1152), 256, 0, stream>>>(he_q, he_k, emb, a_gat);
    prep_weights<<<dim3(800), 256, 0, stream>>>(Wq, Wk, Wout, WTq, WTk, woutT);
    proj_all<<<dim3(144, 8), 256, 0, stream>>>(a_gat, WTq, WTk,
                                               bq, bk, hq_bf, hk_bf, hkT);
    attn_mfma<<<dim3(64, 8), 512, 0, stream>>>(hq_bf, hk_bf, Watt, batt, att);
    pooled_big<<<dim3(64, 2, 8), 256, 0, stream>>>(att, hkT, hq_bf, pool_bf);
    outproj_mfma<<<dim3(64), 256, 0, stream>>>(pool_bf, woutT, partial);
    reduce_out_kernel<<<dim3(76), 256, 0, stream>>>(partial, bout, outv);
    sim_kernel<<<dim3(250), 256, 0, stream>>>(outv, glove, sim);
    lsm_kernel<<<dim3(64), 256, 0, stream>>>(sim, out);
}

// Round 19
// 121.539 us; speedup vs baseline: 1.1108x; 1.0114x over previous
//
#include <hip/hip_runtime.h>
#include <math.h>

#define VOCAB 20000
#define E     300
#define EP    320          // padded K for proj GEMM (5 k-steps of 64)
#define AGP   328          // a_gat row pitch (656B, 16B-aligned)
#define H     1024
#define G     8
#define NOUT  300
#define NP    320          // padded N for outproj
#define KOUT  8192         // G*H
#define NANS  4000
#define B     64
#define NQ    32
#define NK    256

typedef __attribute__((ext_vector_type(8))) short bf16x8;
typedef __attribute__((ext_vector_type(4))) float f32x4;

__device__ inline ushort f2bf(float x) {
    union { float f; unsigned u; } c; c.f = x;
    unsigned r = c.u + 0x7FFF + ((c.u >> 16) & 1);   // RNE
    return (ushort)(r >> 16);
}
__device__ inline float bf2f(ushort x) {
    union { unsigned u; float f; } c; c.u = ((unsigned)x) << 16;
    return c.f;
}
#define MFMA(a, b, c) __builtin_amdgcn_mfma_f32_16x16x32_bf16((a), (b), (c), 0, 0, 0)

// ---------------------------------------------------------------------------
// P0: merged prep. 1952 blocks:
//   id < 1152       : a_gat rows (16/block) from emb gather
//   1152 <= id <1312: WT tiles from Wq/Wk (64h x 64e, f32 LDS bounce)
//   id >= 1312      : woutT tiles from Wout (64k x 64n)
// ---------------------------------------------------------------------------
__global__ __launch_bounds__(256) void prep_all(
    const int* __restrict__ he_q, const int* __restrict__ he_k,
    const float* __restrict__ emb,
    const float* __restrict__ Wq, const float* __restrict__ Wk,
    const float* __restrict__ Wout,
    ushort* __restrict__ a_gat,
    ushort* __restrict__ WTq, ushort* __restrict__ WTk,
    ushort* __restrict__ woutT)
{
    __shared__ __align__(16) float lf[64 * 65];      // 16,640 B
    const int id = blockIdx.x;
    const int t = threadIdx.x;

    if (id < 1152) {                                 // gather
        const int r0 = id * 16;
        for (int i = t; i < 16 * 80; i += 256) {
            int r = r0 + (i / 80), c4 = (i % 80) * 4;
            int row = (r < 2048) ? he_q[r] : he_k[r - 2048];
            ushort4 o{0, 0, 0, 0};
            if (c4 + 4 <= E) {
                float4 v = *(const float4*)(emb + (long)row * E + c4);
                o.x = f2bf(v.x); o.y = f2bf(v.y); o.z = f2bf(v.z); o.w = f2bf(v.w);
            }
            *(ushort4*)(a_gat + (long)r * AGP + c4) = o;
        }
    } else if (id < 1312) {                          // WT tiles
        const int wid = id - 1152;
        const int hT = wid % 16, eT = (wid / 16) % 5, z = wid / 80;
        const float* W = z ? Wk : Wq;
        ushort* WT = z ? WTk : WTq;
        const int h0 = hT * 64, e0 = eT * 64;

        for (int i = t; i < 64 * 64; i += 256) {     // coalesced along h
            int ec = i >> 6, hh = i & 63;
            int e = e0 + ec;
            lf[hh * 65 + ec] = (e < E) ? W[(long)e * H + h0 + hh] : 0.f;
        }
        __syncthreads();
        for (int i = t; i < 64 * 16; i += 256) {     // contiguous along e
            int hh = i >> 4, c = i & 15;
            ushort4 o;
            o.x = f2bf(lf[hh * 65 + c * 4 + 0]);
            o.y = f2bf(lf[hh * 65 + c * 4 + 1]);
            o.z = f2bf(lf[hh * 65 + c * 4 + 2]);
            o.w = f2bf(lf[hh * 65 + c * 4 + 3]);
            *(ushort4*)(WT + (long)(h0 + hh) * EP + e0 + c * 4) = o;
        }
    } else {                                         // woutT tiles
        ushort* td = (ushort*)lf;                    // [64][72]
        const int wid = id - 1312;
        const int k0 = (wid & 127) * 64, n0 = (wid >> 7) * 64;
        for (int i = t; i < 64 * 64; i += 256) {
            int kk = i >> 6, nn = i & 63;
            int n = n0 + nn;
            float v = (n < NOUT) ? Wout[(long)(k0 + kk) * NOUT + n] : 0.f;
            td[nn * 72 + kk] = f2bf(v);
        }
        __syncthreads();
        for (int i = t; i < 64 * 8; i += 256) {
            int nn = i >> 3, c = i & 7;
            *(bf16x8*)(woutT + (long)(n0 + nn) * KOUT + k0 + c * 8) =
                *(const bf16x8*)(&td[nn * 72 + c * 8]);
        }
    }
}

// ---------------------------------------------------------------------------
// P1: merged GEMM for hq and hk from contiguous a_gat. grid (144, 8) x 256:
// 128x128 tile, 4 waves, BK=64 x 5 steps
// ---------------------------------------------------------------------------
__global__ __launch_bounds__(256, 4) void proj_all(
    const ushort* __restrict__ a_gat,
    const ushort* __restrict__ WTq, const ushort* __restrict__ WTk,
    const float* __restrict__ bq, const float* __restrict__ bk,
    ushort* __restrict__ hq_bf, ushort* __restrict__ hk_bf,
    ushort* __restrict__ hkT)
{
    __shared__ ushort lds[2 * 128 * 72];             // 36,864 B (aliased)
    const bool isq = blockIdx.x < 16;
    const int xt = isq ? blockIdx.x : blockIdx.x - 16;
    const ushort* __restrict__ WT = isq ? WTq : WTk;
    const float* __restrict__ bias = isq ? bq : bk;
    ushort* __restrict__ outr = isq ? hq_bf : hk_bf;
    const int r0 = xt * 128;
    const int n0 = blockIdx.y * 128;
    const int t = threadIdx.x;
    const ushort* __restrict__ ag =
        a_gat + (isq ? 0L : 2048L * AGP) + (long)r0 * AGP;

    const int w = t >> 6, l = t & 63, lr = l & 15, lc = l >> 4;
    const int wm = (w >> 1) * 64, wn = (w & 1) * 64;
    const int srow = t >> 3;                         // 32 rows/pass
    const int scol = (t & 7) * 8;                    // 0..56
    ushort* As = lds;                                // [128][72]
    ushort* Bs = lds + 128 * 72;                     // [128][72]
    f32x4 acc[4][4] = {};

    for (int kk = 0; kk < 5; ++kk) {                 // BK=64
        if (kk) __syncthreads();                     // prev reads done
        #pragma unroll
        for (int p = 0; p < 4; ++p) {
            int r = p * 32 + srow;
            *(bf16x8*)(As + r * 72 + scol) =
                *(const bf16x8*)(ag + (long)r * AGP + kk * 64 + scol);
            *(bf16x8*)(Bs + r * 72 + scol) =
                *(const bf16x8*)(WT + (long)(n0 + r) * EP + kk * 64 + scol);
        }
        __syncthreads();

        #pragma unroll
        for (int ks = 0; ks < 2; ++ks) {
            bf16x8 af[4], bf[4];
            #pragma unroll
            for (int mf = 0; mf < 4; ++mf)
                af[mf] = *(const bf16x8*)(As + (wm + mf * 16 + lr) * 72 +
                                          ks * 32 + lc * 8);
            #pragma unroll
            for (int nf = 0; nf < 4; ++nf)
                bf[nf] = *(const bf16x8*)(Bs + (wn + nf * 16 + lr) * 72 +
                                          ks * 32 + lc * 8);
            #pragma unroll
            for (int mf = 0; mf < 4; ++mf)
                #pragma unroll
                for (int nf = 0; nf < 4; ++nf)
                    acc[mf][nf] = MFMA(af[mf], bf[nf], acc[mf][nf]);
        }
    }

    // Epilogue: two 64-row phases through [64][130] (aliased onto As/Bs)
    const int b = r0 >> 8, k0 = r0 & 255;
    #pragma unroll
    for (int ph = 0; ph < 2; ++ph) {
        __syncthreads();                             // K-loop / prev phase reads done
        if (wm == ph * 64) {
            #pragma unroll
            for (int mf = 0; mf < 4; ++mf)
            #pragma unroll
            for (int nf = 0; nf < 4; ++nf) {
                const int col = wn + nf * 16 + lr;
                const float bv = bias[n0 + col];
                #pragma unroll
                for (int r = 0; r < 4; ++r)
                    lds[(mf * 16 + lc * 4 + r) * 130 + col] =
                        f2bf(acc[mf][nf][r] + bv);
            }
        }
        __syncthreads();
        for (int i = t; i < 64 * 16; i += 256) {     // 64 rows x 16 chunks(16B)
            int k = i >> 4, c = i & 15;
            *(bf16x8*)(outr + (long)(r0 + ph * 64 + k) * H + n0 + c * 8) =
                *(const bf16x8*)(lds + k * 130 + c * 8);
        }
        if (!isq) {
            for (int i = t; i < 128 * 8; i += 256) { // 128 d x 8 chunks(16B)
                int d = i >> 3, c = i & 7;
                ushort tmp[8];
                #pragma unroll
                for (int j = 0; j < 8; ++j) tmp[j] = lds[(c * 8 + j) * 130 + d];
                *(bf16x8*)(hkT + (long)b * (H * NK) + (n0 + d) * NK +
                           k0 + ph * 64 + c * 8) = *(const bf16x8*)(tmp);
            }
        }
    }
}

// ---------------------------------------------------------------------------
// P2+P3 fused: att[b,g,q,k] = softmax_joint( (hq*watt_g) @ hk^T + batt[g] )
//     block=(b,g), 512 thr / 8 waves, BK=64 LDS-staged; A scaled during stage
// ---------------------------------------------------------------------------
__global__ __launch_bounds__(512) void attn_mfma(
    const ushort* __restrict__ hq, const ushort* __restrict__ hk,
    const float* __restrict__ watt, const float* __restrict__ batt,
    ushort* __restrict__ att)
{
    const int b = blockIdx.x, g = blockIdx.y;
    const int t = threadIdx.x, w = t >> 6, l = t & 63, lr = l & 15, lc = l >> 4;
    __shared__ float wg[H];                          //  4 KB
    __shared__ ushort As[32 * 72];                   //  4.6 KB
    __shared__ ushort Bs[256 * 72];                  // 36.9 KB
    __shared__ float red[16];

    for (int i = t; i < H; i += 512) wg[i] = watt[i * G + g];

    f32x4 acc[2][2] = {};
    __syncthreads();                                 // wg ready

    for (int kk = 0; kk < 16; ++kk) {                // BK=64
        if (kk) __syncthreads();                     // prev reads done
        if (t < 256) {                               // A: 32 x 64, scale on stage
            int r = t >> 3, c8 = (t & 7) * 8;
            bf16x8 hv = *(const bf16x8*)(hq + (b * NQ + r) * H + kk * 64 + c8);
            bf16x8 o;
            #pragma unroll
            for (int j = 0; j < 8; ++j)
                o[j] = (short)f2bf(bf2f((ushort)hv[j]) * wg[kk * 64 + c8 + j]);
            *(bf16x8*)(As + r * 72 + c8) = o;
        }
        #pragma unroll
        for (int p = 0; p < 4; ++p) {                // B: 256 x 64 coalesced
            int j = t + 512 * p;
            int r = j >> 3, c8 = (j & 7) * 8;
            *(bf16x8*)(Bs + r * 72 + c8) =
                *(const bf16x8*)(hk + (b * NK + r) * H + kk * 64 + c8);
        }
        __syncthreads();

        #pragma unroll
        for (int ks = 0; ks < 2; ++ks) {
            bf16x8 a0 = *(const bf16x8*)(As + lr * 72 + ks * 32 + lc * 8);
            bf16x8 a1 = *(const bf16x8*)(As + (16 + lr) * 72 + ks * 32 + lc * 8);
            bf16x8 b0 = *(const bf16x8*)(Bs + (w * 32 + lr) * 72 + ks * 32 + lc * 8);
            bf16x8 b1 = *(const bf16x8*)(Bs + (w * 32 + 16 + lr) * 72 + ks * 32 + lc * 8);
            acc[0][0] = MFMA(a0, b0, acc[0][0]);
            acc[0][1] = MFMA(a0, b1, acc[0][1]);
            acc[1][0] = MFMA(a1, b0, acc[1][0]);
            acc[1][1] = MFMA(a1, b1, acc[1][1]);
        }
    }

    const float bg = batt[g];
    float lm = -1e30f;
    #pragma unroll
    for (int mt = 0; mt < 2; ++mt)
    #pragma unroll
    for (int nf = 0; nf < 2; ++nf)
    #pragma unroll
    for (int r = 0; r < 4; ++r) {
        acc[mt][nf][r] += bg;
        lm = fmaxf(lm, acc[mt][nf][r]);
    }
    #pragma unroll
    for (int off = 32; off; off >>= 1) lm = fmaxf(lm, __shfl_xor(lm, off));
    if (l == 0) red[w] = lm;
    __syncthreads();
    float gm = red[0];
    #pragma unroll
    for (int i = 1; i < 8; ++i) gm = fmaxf(gm, red[i]);

    float ls = 0.f;
    #pragma unroll
    for (int mt = 0; mt < 2; ++mt)
    #pragma unroll
    for (int nf = 0; nf < 2; ++nf)
    #pragma unroll
    for (int r = 0; r < 4; ++r) {
        float e = __expf(acc[mt][nf][r] - gm);
        acc[mt][nf][r] = e;
        ls += e;
    }
    #pragma unroll
    for (int off = 32; off; off >>= 1) ls += __shfl_xor(ls, off);
    if (l == 0) red[8 + w] = ls;
    __syncthreads();
    float sum = red[8];
    #pragma unroll
    for (int i = 9; i < 16; ++i) sum += red[i];
    const float inv = 1.f / sum;

    ushort* op = att + (b * 8 + g) * (NQ * NK);
    #pragma unroll
    for (int mt = 0; mt < 2; ++mt)
    #pragma unroll
    for (int nf = 0; nf < 2; ++nf)
    #pragma unroll
    for (int r = 0; r < 4; ++r)
        op[(mt * 16 + lc * 4 + r) * NK + w * 32 + nf * 16 + lr] =
            f2bf(acc[mt][nf][r] * inv);
}

// ---------------------------------------------------------------------------
// P4: pooled as GEMM; BK=64 x 4 steps; q-fold in-register
//     grid (64 b, 2 mt, 8 nt) x 256; (256,4) for TLP
// ---------------------------------------------------------------------------
__global__ __launch_bounds__(256, 4) void pooled_big(
    const ushort* __restrict__ att, const ushort* __restrict__ hkT,
    const ushort* __restrict__ hq, ushort* __restrict__ pooled_bf)
{
    __shared__ ushort lds[2 * 128 * 72];             // 36,864 B (aliased)
    const int b = blockIdx.x, mt = blockIdx.y, nt = blockIdx.z;
    const int t = threadIdx.x;
    const int w = t >> 6, l = t & 63, lr = l & 15, lc = l >> 4;
    const int wm = (w >> 1) * 64, wn = (w & 1) * 64;
    const int srow = t >> 3;                         // 32 rows/pass
    const int scol = (t & 7) * 8;                    // 0..56
    ushort* As = lds;                                // [128][72]  att tile
    ushort* Bs = lds + 128 * 72;                     // [128][72]  hkT tile
    const ushort* ab = att + (long)b * (G * NQ * NK) + (long)mt * 128 * NK;
    const ushort* bb = hkT + (long)b * (H * NK) + (long)nt * 128 * NK;
    f32x4 acc[4][4] = {};

    for (int kk = 0; kk < 4; ++kk) {                 // K=256, BK=64
        if (kk) __syncthreads();
        #pragma unroll
        for (int p = 0; p < 4; ++p) {
            int r = p * 32 + srow;
            *(bf16x8*)(As + r * 72 + scol) =
                *(const bf16x8*)(ab + (long)r * NK + kk * 64 + scol);
            *(bf16x8*)(Bs + r * 72 + scol) =
                *(const bf16x8*)(bb + (long)r * NK + kk * 64 + scol);
        }
        __syncthreads();

        #pragma unroll
        for (int ks = 0; ks < 2; ++ks) {
            bf16x8 af[4], bf[4];
            #pragma unroll
            for (int mf = 0; mf < 4; ++mf)
                af[mf] = *(const bf16x8*)(As + (wm + mf * 16 + lr) * 72 +
                                          ks * 32 + lc * 8);
            #pragma unroll
            for (int nf = 0; nf < 4; ++nf)
                bf[nf] = *(const bf16x8*)(Bs + (wn + nf * 16 + lr) * 72 +
                                          ks * 32 + lc * 8);
            #pragma unroll
            for (int mf = 0; mf < 4; ++mf)
                #pragma unroll
                for (int nf = 0; nf < 4; ++nf)
                    acc[mf][nf] = MFMA(af[mf], bf[nf], acc[mf][nf]);
        }
    }
    __syncthreads();                                 // loop reads done

    // stage hq tile [32 q][128 d] (cols nt*128..) pitch 136
    for (int i = t; i < 32 * 16; i += 256) {
        int r = i >> 4, c8 = (i & 15) * 8;
        *(bf16x8*)(lds + r * 136 + c8) =
            *(const bf16x8*)(hq + ((long)b * NQ + r) * H + nt * 128 + c8);
    }
    __syncthreads();

    // in-register q-fold: wave's 64 rows = 2 g-groups (gl = mf>>1)
    float s[2][4] = {};
    #pragma unroll
    for (int nf = 0; nf < 4; ++nf) {
        const int col = wn + nf * 16 + lr;           // tile col 0..127
        #pragma unroll
        for (int mf = 0; mf < 4; ++mf) {
            #pragma unroll
            for (int r = 0; r < 4; ++r) {
                const int q = (wm + mf * 16 + lc * 4 + r) & 31;
                s[mf >> 1][nf] += acc[mf][nf][r] * bf2f(lds[q * 136 + col]);
            }
        }
    }
    #pragma unroll
    for (int gl = 0; gl < 2; ++gl)
    #pragma unroll
    for (int nf = 0; nf < 4; ++nf) {
        float v = s[gl][nf];
        v += __shfl_xor(v, 16);
        v += __shfl_xor(v, 32);
        if (l < 16) {
            const int g = mt * 4 + (wm >> 5) + gl;   // wm/32 in {0,2}
            const int d = nt * 128 + wn + nf * 16 + lr;
            pooled_bf[((long)b * G + g) * H + d] = f2bf(v);
        }
    }
}

// ---------------------------------------------------------------------------
// P5: out = pooled_bf[64,8192] @ woutT^T  (MFMA, 64-way k-split)
// ---------------------------------------------------------------------------
__global__ __launch_bounds__(256) void outproj_mfma(
    const ushort* __restrict__ pooled_bf, const ushort* __restrict__ woutT,
    float* __restrict__ partial)
{
    const int ks = blockIdx.x;
    const int k0 = ks * 128;
    const int t = threadIdx.x, w = t >> 6, l = t & 63, lr = l & 15, lc = l >> 4;
    const ushort* ap = pooled_bf + lr * KOUT + k0 + lc * 8;
    const ushort* bp = woutT + (w * 80 + lr) * KOUT + k0 + lc * 8;
    f32x4 acc[4][5] = {};

    #pragma unroll
    for (int kk = 0; kk < 4; ++kk) {
        bf16x8 a[4];
        #pragma unroll
        for (int mt = 0; mt < 4; ++mt)
            a[mt] = *(const bf16x8*)(ap + mt * 16 * KOUT + kk * 32);
        #pragma unroll
        for (int nt = 0; nt < 5; ++nt) {
            bf16x8 bfr = *(const bf16x8*)(bp + nt * 16 * KOUT + kk * 32);
            #pragma unroll
            for (int mt = 0; mt < 4; ++mt)
                acc[mt][nt] = MFMA(a[mt], bfr, acc[mt][nt]);
        }
    }

    #pragma unroll
    for (int mt = 0; mt < 4; ++mt)
    #pragma unroll
    for (int nt = 0; nt < 5; ++nt)
    #pragma unroll
    for (int r = 0; r < 4; ++r) {
        const int bb = mt * 16 + lc * 4 + r;
        const int n = w * 80 + nt * 16 + lr;
        partial[(ks * B + bb) * NP + n] = acc[mt][nt][r];
    }
}

// ---------------------------------------------------------------------------
// P6: outv[b,n] = bout[n] + sum_ks partial[ks,b,n]   (76 blocks x 256)
// ---------------------------------------------------------------------------
__global__ __launch_bounds__(256) void reduce_out_kernel(
    const float* __restrict__ partial, const float* __restrict__ bout,
    float* __restrict__ outv)
{
    const int i = blockIdx.x * 256 + threadIdx.x;   // 64*304
    if (i >= B * 304) return;
    const int b = i / 304, n = i % 304;
    float acc = 0.f;
    if (n < NOUT) {
        acc = bout[n];
        for (int ks = 0; ks < 64; ++ks)
            acc += partial[(ks * B + b) * NP + n];
    }
    outv[b * 304 + n] = acc;
}

// ---------------------------------------------------------------------------
// S1: sim[b,a] = outv[b]·glove[a]  — 250 blocks x (16 answers x 64 b)
//     glove tile in LDS (19.7KB); outv read from global (L2-hot, broadcast)
// ---------------------------------------------------------------------------
__global__ __launch_bounds__(256) void sim_kernel(
    const float* __restrict__ outv, const float* __restrict__ glove,
    float* __restrict__ sim)
{
    __shared__ __align__(16) float gl[16][308];
    const int t = threadIdx.x;
    const int a0 = blockIdx.x * 16;

    for (int i = t; i < 16 * 75; i += 256) {
        int r = i / 75, c = i % 75;
        *(float4*)(&gl[r][c * 4]) = *(const float4*)(&glove[(a0 + r) * NOUT + c * 4]);
    }
    __syncthreads();

    const int a = t & 15, bg = t >> 4;   // 16 answers x 16 b-groups(4 b each)
    float acc[4] = {};
    for (int k4 = 0; k4 < 75; ++k4) {
        float4 g = *(const float4*)(&gl[a][k4 * 4]);
        #pragma unroll
        for (int bi = 0; bi < 4; ++bi) {
            float4 o = *(const float4*)(&outv[(bg * 4 + bi) * 304 + k4 * 4]);
            acc[bi] += g.x * o.x + g.y * o.y + g.z * o.z + g.w * o.w;
        }
    }
    #pragma unroll
    for (int bi = 0; bi < 4; ++bi)
        sim[(bg * 4 + bi) * NANS + a0 + a] = acc[bi];
}

// ---------------------------------------------------------------------------
// S2: per-b log_softmax over 4000, write d_out
// ---------------------------------------------------------------------------
__global__ __launch_bounds__(256) void lsm_kernel(
    const float* __restrict__ sim, float* __restrict__ dout)
{
    const int b = blockIdx.x, t = threadIdx.x;
    const float* p = sim + b * NANS;
    __shared__ float red[4];

    float4 v[4];
    float lm = -1e30f;
    #pragma unroll
    for (int j = 0; j < 4; ++j) {
        int i = t + j * 256;
        if (i < 1000) {
            v[j] = ((const float4*)p)[i];
            lm = fmaxf(lm, fmaxf(fmaxf(v[j].x, v[j].y), fmaxf(v[j].z, v[j].w)));
        }
    }
    #pragma unroll
    for (int off = 32; off; off >>= 1) lm = fmaxf(lm, __shfl_xor(lm, off));
    if ((t & 63) == 0) red[t >> 6] = lm;
    __syncthreads();
    const float gm = fmaxf(fmaxf(red[0], red[1]), fmaxf(red[2], red[3]));

    float ls = 0.f;
    #pragma unroll
    for (int j = 0; j < 4; ++j) {
        int i = t + j * 256;
        if (i < 1000)
            ls += __expf(v[j].x - gm) + __expf(v[j].y - gm) +
                  __expf(v[j].z - gm) + __expf(v[j].w - gm);
    }
    #pragma unroll
    for (int off = 32; off; off >>= 1) ls += __shfl_xor(ls, off);
    __syncthreads();
    if ((t & 63) == 0) red[t >> 6] = ls;
    __syncthreads();
    const float sh = gm + logf(red[0] + red[1] + red[2] + red[3]);

    #pragma unroll
    for (int j = 0; j < 4; ++j) {
        int i = t + j * 256;
        if (i < 1000) {
            float4 o;
            o.x = v[j].x - sh; o.y = v[j].y - sh;
            o.z = v[j].z - sh; o.w = v[j].w - sh;
            ((float4*)(dout + b * NANS))[i] = o;
        }
    }
}

// ---------------------------------------------------------------------------
extern "C" void kernel_launch(void* const* d_in, const int* in_sizes, int n_in,
                              void* d_out, int out_size, void* d_ws, size_t ws_size,
                              hipStream_t stream)
{
    (void)in_sizes; (void)n_in; (void)out_size; (void)ws_size;
    const int*   he_q  = (const int*)  d_in[0];
    const int*   he_k  = (const int*)  d_in[1];
    const float* emb   = (const float*)d_in[2];
    const float* Wq    = (const float*)d_in[3];
    const float* bq    = (const float*)d_in[4];
    const float* Wk    = (const float*)d_in[5];
    const float* bk    = (const float*)d_in[6];
    const float* Watt  = (const float*)d_in[7];
    const float* batt  = (const float*)d_in[8];
    const float* Wout  = (const float*)d_in[9];
    const float* bout  = (const float*)d_in[10];
    const float* glove = (const float*)d_in[11];
    float* out = (float*)d_out;

    ushort* WTq    = (ushort*)d_ws;                  //    327,680 sh
    ushort* WTk    = WTq + 327680;                   //    327,680 sh
    ushort* a_gat  = WTk + 327680;                   //  6,045,696 sh  [18432][328]
    ushort* hq_bf  = a_gat + 6045696;                //  2,097,152 sh  [b][q][d]
    ushort* hk_bf  = hq_bf + 2097152;                // 16,777,216 sh  [b][k][d]
    ushort* hkT    = hk_bf + 16777216;               // 16,777,216 sh  [b][d][k]
    ushort* pool_bf= hkT + 16777216;                 //    524,288 sh  [b][g*H+d]
    ushort* woutT  = pool_bf + 524288;               //  2,621,440 sh  [320][8192]
    ushort* att    = woutT + 2621440;                //  4,194,304 sh
    float*  partial= (float*)(att + 4194304);        //  1,310,720 f32 [64][64][320]
    float*  outv   = partial + 1310720;              //     19,456 f32
    float*  sim    = outv + 19456;                   //    256,000 f32

    prep_all<<<dim3(1952), 256, 0, stream>>>(he_q, he_k, emb, Wq, Wk, Wout,
                                             a_gat, WTq, WTk, woutT);
    proj_all<<<dim3(144, 8), 256, 0, stream>>>(a_gat, WTq, WTk,
                                               bq, bk, hq_bf, hk_bf, hkT);
    attn_mfma<<<dim3(64, 8), 512, 0, stream>>>(hq_bf, hk_bf, Watt, batt, att);
    pooled_big<<<dim3(64, 2, 8), 256, 0, stream>>>(att, hkT, hq_bf, pool_bf);
    outproj_mfma<<<dim3(64), 256, 0, stream>>>(pool_bf, woutT, partial);
    reduce_out_kernel<<<dim3(76), 256, 0, stream>>>(partial, bout, outv);
    sim_kernel<<<dim3(250), 256, 0, stream>>>(outv, glove, sim);
    lsm_kernel<<<dim3(64), 256, 0, stream>>>(sim, out);
}